// Round 5
// baseline (385.795 us; speedup 1.0000x reference)
//
#include <hip/hip_runtime.h>
#include <hip/hip_bf16.h>

#define NN 50000
#define EE 850000
#define NBLK_SCAN 98  // ceil(50000/512)

typedef unsigned short u16;
using short8 = __attribute__((ext_vector_type(8))) short;
using f32x4  = __attribute__((ext_vector_type(4))) float;

__device__ __forceinline__ float bf2f(u16 u) {
    union { unsigned int i; float f; } v; v.i = ((unsigned int)u) << 16; return v.f;
}
__device__ __forceinline__ u16 f2bf(float f) {
    __hip_bfloat16 h = __float2bfloat16(f);
    return *reinterpret_cast<u16*>(&h);
}

__device__ __forceinline__ float ld1(const void* X, size_t i, bool f32m) {
    return f32m ? ((const float*)X)[i] : bf2f(((const u16*)X)[i]);
}
__device__ __forceinline__ void load4(const void* X, size_t g, bool f32m, float o[4]) {
    if (f32m) {
        float4 v = ((const float4*)X)[g];
        o[0] = v.x; o[1] = v.y; o[2] = v.z; o[3] = v.w;
    } else {
        ushort4 v = ((const ushort4*)X)[g];
        o[0] = bf2f(v.x); o[1] = bf2f(v.y); o[2] = bf2f(v.z); o[3] = bf2f(v.w);
    }
}

// ---- block 0: dtype detect; blocks 1..196: zero deg ----
__global__ void k_detect(const u16* __restrict__ hh, int* __restrict__ flag,
                         int* __restrict__ deg) {
    if (blockIdx.x != 0) {
        int i = (blockIdx.x - 1) * 256 + threadIdx.x;
        if (i < NN) deg[i] = 0;
        return;
    }
    __shared__ int sm[256];
    int t = threadIdx.x;
    int c = 0;
    for (int i = 0; i < 16; ++i) {
        u16 u = hh[t * 16 + i];
        int e = (u >> 7) & 0xFF;
        if (e != 0 && (e < 90 || e > 160)) ++c;
    }
    sm[t] = c;
    __syncthreads();
    for (int s = 128; s > 0; s >>= 1) {
        if (t < s) sm[t] += sm[t + s];
        __syncthreads();
    }
    if (t == 0) *flag = (sm[0] > 200) ? 1 : 0;
}

// ---- fused prep: 0..511 B-transpose, 512..527 attn vecs, rest deg+rank ----
__global__ void k_prep(const void* __restrict__ W1s, const void* __restrict__ al1,
                       const void* __restrict__ W1d, const void* __restrict__ ar1,
                       const void* __restrict__ W2s, const void* __restrict__ al2,
                       const void* __restrict__ W2d, const void* __restrict__ ar2,
                       const void* __restrict__ Wres2, const int* __restrict__ dst,
                       u16* __restrict__ BT1, u16* __restrict__ BT2,
                       float* __restrict__ wl1, float* __restrict__ wr1,
                       float* __restrict__ wl2, float* __restrict__ wr2,
                       int* __restrict__ deg, int* __restrict__ eorder,
                       const int* __restrict__ mode) {
    int bid = blockIdx.x;
    if (bid >= 528) {
        int e = (bid - 528) * 256 + threadIdx.x;
        if (e < EE) {
            int r = atomicAdd(&deg[dst[e]], 1);
            eorder[e] = r;
        }
        return;
    }
    bool f32m = (*mode) != 0;
    if (bid < 512) {
        int id = bid * 256 + threadIdx.x;  // 0..131071
        int which = id >> 16;
        int rem = id & 65535;
        int n = rem >> 8, k = rem & 255;
        if (which == 0) {
            BT1[n * 256 + k] = f2bf(ld1(W1s, (size_t)k * 256 + n, f32m));
        } else {
            float v = (n < 128) ? ld1(W2s, (size_t)k * 128 + n, f32m)
                                : ld1(Wres2, (size_t)k * 128 + (n - 128), f32m);
            BT2[n * 256 + k] = f2bf(v);
        }
    } else {
        int id = (bid - 512) * 256 + threadIdx.x;  // 0..4095
        int which = id >> 10;
        int rem = id & 1023;
        int k = rem >> 2, h = rem & 3;
        float s = 0.f;
        if (which == 0) {
            for (int d = 0; d < 64; ++d) s += ld1(W1s, k * 256 + h * 64 + d, f32m) * ld1(al1, h * 64 + d, f32m);
            wl1[k * 4 + h] = s;
        } else if (which == 1) {
            for (int d = 0; d < 64; ++d) s += ld1(W1d, k * 256 + h * 64 + d, f32m) * ld1(ar1, h * 64 + d, f32m);
            wr1[k * 4 + h] = s;
        } else if (which == 2) {
            for (int d = 0; d < 32; ++d) s += ld1(W2s, k * 128 + h * 32 + d, f32m) * ld1(al2, h * 32 + d, f32m);
            wl2[k * 4 + h] = s;
        } else {
            for (int d = 0; d < 32; ++d) s += ld1(W2d, k * 128 + h * 32 + d, f32m) * ld1(ar2, h * 32 + d, f32m);
            wr2[k * 4 + h] = s;
        }
    }
}

// ---- CSR scan stage 1: per-block inclusive scan + block sums ----
__global__ void k_scan1(const int* __restrict__ deg, int* __restrict__ rowptr,
                        int* __restrict__ bsum) {
    __shared__ int sm[512];
    int t = threadIdx.x;
    int i = blockIdx.x * 512 + t;
    int v = (i < NN) ? deg[i] : 0;
    int x = v;
    sm[t] = x;
    __syncthreads();
    for (int off = 1; off < 512; off <<= 1) {
        int y = (t >= off) ? sm[t - off] : 0;
        __syncthreads();
        x += y;
        sm[t] = x;
        __syncthreads();
    }
    if (i < NN) rowptr[i] = x - v;
    if (t == 511) bsum[blockIdx.x] = x;
}

// ---- fused: blocks 0..195 scan-finalize; rest eler1 + h->bf16 conversion ----
__global__ void k_scan3_eler1(int* __restrict__ rowptr, const int* __restrict__ bsum,
                              const void* __restrict__ X, u16* __restrict__ hb,
                              const float* __restrict__ wl, const float* __restrict__ wr,
                              float* __restrict__ el, float* __restrict__ er,
                              const int* __restrict__ mode) {
    int bid = blockIdx.x;
    if (bid < 196) {
        __shared__ int sm[NBLK_SCAN];
        int t = threadIdx.x;
        if (t < NBLK_SCAN) sm[t] = bsum[t];
        __syncthreads();
        int g = bid >> 1;  // each block's 256 indices lie in one 512-group
        int pre = 0;
        for (int j = 0; j < g; ++j) pre += sm[j];  // LDS broadcast, uniform
        int i = bid * 256 + t;
        if (i < NN) {
            rowptr[i] += pre;
            if (i == 0) rowptr[NN] = EE;
        }
        return;
    }
    bool f32m = (*mode) != 0;
    int wave = threadIdx.x >> 6, lane = threadIdx.x & 63;
    int node = (bid - 196) * 4 + wave;
    float a[4];
    load4(X, (size_t)node * 64 + lane, f32m, a);
    // persist bf16 copy of h: feeds GEMM1 A-staging + agg1 residual
    ushort4 hv = {f2bf(a[0]), f2bf(a[1]), f2bf(a[2]), f2bf(a[3])};
    ((ushort4*)hb)[(size_t)node * 64 + lane] = hv;
    float accl[4] = {0, 0, 0, 0}, accr[4] = {0, 0, 0, 0};
    int k0 = lane * 4;
#pragma unroll
    for (int j = 0; j < 4; ++j) {
        float4 wlv = ((const float4*)wl)[k0 + j];
        float4 wrv = ((const float4*)wr)[k0 + j];
        accl[0] += a[j] * wlv.x; accl[1] += a[j] * wlv.y;
        accl[2] += a[j] * wlv.z; accl[3] += a[j] * wlv.w;
        accr[0] += a[j] * wrv.x; accr[1] += a[j] * wrv.y;
        accr[2] += a[j] * wrv.z; accr[3] += a[j] * wrv.w;
    }
#pragma unroll
    for (int off = 32; off > 0; off >>= 1) {
#pragma unroll
        for (int t = 0; t < 4; ++t) {
            accl[t] += __shfl_down(accl[t], off, 64);
            accr[t] += __shfl_down(accr[t], off, 64);
        }
    }
    if (lane == 0) {
        float4 vl = {accl[0], accl[1], accl[2], accl[3]};
        float4 vr = {accr[0], accr[1], accr[2], accr[3]};
        ((float4*)el)[node] = vl;
        ((float4*)er)[node] = vr;
    }
}

// ---- edge-parallel weight gen (atomic-free): slot = rowptr[d]+eorder[e] ----
__global__ void k_awgen(const int* __restrict__ src, const int* __restrict__ dst,
                        const int* __restrict__ eorder, const int* __restrict__ rowptr,
                        const float* __restrict__ el, const float* __restrict__ er,
                        u16* __restrict__ aw, int* __restrict__ csrc, int writeCsrc) {
    int e = blockIdx.x * 256 + threadIdx.x;
    if (e >= EE) return;
    int s = src[e], d = dst[e];
    int slot = rowptr[d] + eorder[e];
    if (writeCsrc) csrc[slot] = s;
    float4 eL = ((const float4*)el)[s];
    float4 eR = ((const float4*)er)[d];
    float ev[4] = {eL.x + eR.x, eL.y + eR.y, eL.z + eR.z, eL.w + eR.w};
    ushort4 o;
    u16* op = (u16*)&o;
#pragma unroll
    for (int t = 0; t < 4; ++t) {
        float x = ev[t];
        x = x > 0.f ? x : 0.2f * x;
        x = fminf(fmaxf(x, -60.f), 60.f);
        op[t] = f2bf(__expf(x));
    }
    ((ushort4*)aw)[slot] = o;
}

// ---- MFMA GEMM: C[M][256] bf16 = A[M][256] @ B (BT transposed [256n][256k]) ----
// A always bf16 (hb). Epilogue restages C via swizzled LDS -> coalesced stores.
__global__ void k_gemm_mfma(const u16* __restrict__ A,
                            const u16* __restrict__ BT, u16* __restrict__ C) {
    __shared__ u16 smem[128 * 72 * 2];  // At|Bt, reused as Ct (32768 B)
    u16* At = smem;
    u16* Bt = smem + 128 * 72;
    int t = threadIdx.x;
    int lane = t & 63, w = t >> 6;
    int mt = blockIdx.x >> 1, nt = blockIdx.x & 1;
    int m0 = mt * 128, n0 = nt * 128;
    int wr = (w >> 1) * 64, wc = (w & 1) * 64;
    f32x4 acc[4][4] = {};
    int q = lane >> 4, cl = lane & 15;

    for (int ph = 0; ph < 4; ++ph) {
        int kb = ph * 64;
        for (int it = 0; it < 4; ++it) {
            int c = it * 256 + t;
            int row = c >> 3, c8 = c & 7;
            int rowg = m0 + row;
            float4 av;
            if (rowg < NN) {
                av = *(const float4*)(A + (size_t)rowg * 256 + kb + c8 * 8);
            } else {
                av = make_float4(0.f, 0.f, 0.f, 0.f);
            }
            *(float4*)&At[row * 72 + c8 * 8] = av;
            float4 bv = *(const float4*)(BT + (size_t)(n0 + row) * 256 + kb + c8 * 8);
            *(float4*)&Bt[row * 72 + c8 * 8] = bv;
        }
        __syncthreads();
#pragma unroll
        for (int ks = 0; ks < 2; ++ks) {
            short8 af[4], bf[4];
#pragma unroll
            for (int i = 0; i < 4; ++i)
                af[i] = *(const short8*)&At[(wr + i * 16 + cl) * 72 + ks * 32 + q * 8];
#pragma unroll
            for (int j = 0; j < 4; ++j)
                bf[j] = *(const short8*)&Bt[(wc + j * 16 + cl) * 72 + ks * 32 + q * 8];
#pragma unroll
            for (int i = 0; i < 4; ++i)
#pragma unroll
                for (int j = 0; j < 4; ++j)
                    acc[i][j] = __builtin_amdgcn_mfma_f32_16x16x32_bf16(af[i], bf[j], acc[i][j], 0, 0, 0);
        }
        __syncthreads();
    }
    // epilogue: acc -> swizzled LDS (conflict-free) -> coalesced dwordx4 stores
    u16* Ct = smem;
    int sw_w = q << 1;
#pragma unroll
    for (int i = 0; i < 4; ++i)
#pragma unroll
        for (int j = 0; j < 4; ++j) {
            int colb = wc + j * 16 + cl;
            int chunk = (colb >> 3) ^ sw_w;
#pragma unroll
            for (int r = 0; r < 4; ++r) {
                int row = wr + i * 16 + q * 4 + r;
                Ct[row * 128 + chunk * 8 + (colb & 7)] = f2bf(acc[i][j][r]);
            }
        }
    __syncthreads();
#pragma unroll
    for (int it = 0; it < 8; ++it) {
        int c = it * 256 + t;        // 0..2047 chunks of 16 B
        int row = c >> 4, k16 = c & 15;
        int mrow = m0 + row;
        if (mrow < NN) {
            int phys = k16 ^ (((row >> 2) & 3) << 1);
            float4 v = *(const float4*)&Ct[row * 128 + phys * 8];
            *(float4*)&C[(size_t)mrow * 256 + n0 + k16 * 8] = v;
        }
    }
}

// ---- layer-1 aggregation: weighted gather (r0 loop) + bf16 residual + eler2 ----
// hb doubles as residual input and h1 output (same element, same thread).
__global__ void k_agg1(const int* __restrict__ rowptr, const int* __restrict__ csrc,
                       const u16* __restrict__ aw, const u16* __restrict__ fs,
                       u16* __restrict__ hb,
                       const float* __restrict__ wl2, const float* __restrict__ wr2,
                       float* __restrict__ el2, float* __restrict__ er2) {
    int wave = threadIdx.x >> 6, lane = threadIdx.x & 63;
    int node = blockIdx.x * 4 + wave;
    int beg = rowptr[node], end = rowptr[node + 1];
    int head = lane >> 4;
    float a0 = 0.f, a1 = 0.f, a2 = 0.f, a3 = 0.f, ll = 0.f;
#pragma unroll 8
    for (int p = beg; p < end; ++p) {
        int s = csrc[p];
        float pw = bf2f(aw[(size_t)p * 4 + head]);
        ushort4 fv = *(const ushort4*)(fs + (size_t)s * 256 + lane * 4);
        ll += pw;
        a0 += pw * bf2f(fv.x);
        a1 += pw * bf2f(fv.y);
        a2 += pw * bf2f(fv.z);
        a3 += pw * bf2f(fv.w);
    }
    float rinv = 1.f / ll;
    ushort4 rv = ((const ushort4*)hb)[(size_t)node * 64 + lane];
    float v0 = a0 * rinv + bf2f(rv.x), v1 = a1 * rinv + bf2f(rv.y);
    float v2 = a2 * rinv + bf2f(rv.z), v3 = a3 * rinv + bf2f(rv.w);
    v0 = v0 > 0.f ? v0 : __expf(v0) - 1.f;
    v1 = v1 > 0.f ? v1 : __expf(v1) - 1.f;
    v2 = v2 > 0.f ? v2 : __expf(v2) - 1.f;
    v3 = v3 > 0.f ? v3 : __expf(v3) - 1.f;
    ushort4 o = {f2bf(v0), f2bf(v1), f2bf(v2), f2bf(v3)};
    ((ushort4*)hb)[(size_t)node * 64 + lane] = o;
    // fused eler2: lane owns h1 cols lane*4..+3
    float4 w0 = ((const float4*)wl2)[lane * 4 + 0];
    float4 w1 = ((const float4*)wl2)[lane * 4 + 1];
    float4 w2 = ((const float4*)wl2)[lane * 4 + 2];
    float4 w3 = ((const float4*)wl2)[lane * 4 + 3];
    float4 r0 = ((const float4*)wr2)[lane * 4 + 0];
    float4 r1 = ((const float4*)wr2)[lane * 4 + 1];
    float4 r2 = ((const float4*)wr2)[lane * 4 + 2];
    float4 r3 = ((const float4*)wr2)[lane * 4 + 3];
    float acl[4], acr[4];
    acl[0] = v0 * w0.x + v1 * w1.x + v2 * w2.x + v3 * w3.x;
    acl[1] = v0 * w0.y + v1 * w1.y + v2 * w2.y + v3 * w3.y;
    acl[2] = v0 * w0.z + v1 * w1.z + v2 * w2.z + v3 * w3.z;
    acl[3] = v0 * w0.w + v1 * w1.w + v2 * w2.w + v3 * w3.w;
    acr[0] = v0 * r0.x + v1 * r1.x + v2 * r2.x + v3 * r3.x;
    acr[1] = v0 * r0.y + v1 * r1.y + v2 * r2.y + v3 * r3.y;
    acr[2] = v0 * r0.z + v1 * r1.z + v2 * r2.z + v3 * r3.z;
    acr[3] = v0 * r0.w + v1 * r1.w + v2 * r2.w + v3 * r3.w;
#pragma unroll
    for (int off = 32; off > 0; off >>= 1) {
#pragma unroll
        for (int t = 0; t < 4; ++t) {
            acl[t] += __shfl_down(acl[t], off, 64);
            acr[t] += __shfl_down(acr[t], off, 64);
        }
    }
    if (lane == 0) {
        float4 vl = {acl[0], acl[1], acl[2], acl[3]};
        float4 vr = {acr[0], acr[1], acr[2], acr[3]};
        ((float4*)el2)[node] = vl;
        ((float4*)er2)[node] = vr;
    }
}

// ---- layer-2 aggregation: weighted gather + residual + head-mean ----
__global__ void k_agg2(const int* __restrict__ rowptr, const int* __restrict__ csrc,
                       const u16* __restrict__ aw, const u16* __restrict__ c2,
                       void* __restrict__ out, const int* __restrict__ mode) {
    bool f32m = (*mode) != 0;
    int wave = threadIdx.x >> 6, lane = threadIdx.x & 63;
    int node = blockIdx.x * 4 + wave;
    int beg = rowptr[node], end = rowptr[node + 1];
    int head = lane >> 4;
    float a0 = 0.f, a1 = 0.f, ll = 0.f;
#pragma unroll 8
    for (int p = beg; p < end; ++p) {
        int s = csrc[p];
        float pw = bf2f(aw[(size_t)p * 4 + head]);
        ushort2 fv = *(const ushort2*)(c2 + (size_t)s * 256 + lane * 2);
        ll += pw;
        a0 += pw * bf2f(fv.x);
        a1 += pw * bf2f(fv.y);
    }
    float rinv = 1.f / ll;
    ushort2 rv = *(const ushort2*)(c2 + (size_t)node * 256 + 128 + lane * 2);
    float o0 = a0 * rinv + bf2f(rv.x);
    float o1 = a1 * rinv + bf2f(rv.y);
    o0 += __shfl_xor(o0, 16, 64); o0 += __shfl_xor(o0, 32, 64);
    o1 += __shfl_xor(o1, 16, 64); o1 += __shfl_xor(o1, 32, 64);
    if (lane < 16) {
        float v0 = 0.25f * o0, v1 = 0.25f * o1;
        size_t oi = (size_t)node * 32 + lane * 2;
        if (f32m) {
            ((float*)out)[oi] = v0;
            ((float*)out)[oi + 1] = v1;
        } else {
            ushort2 ov = {f2bf(v0), f2bf(v1)};
            *(ushort2*)((u16*)out + oi) = ov;
        }
    }
}

extern "C" void kernel_launch(void* const* d_in, const int* in_sizes, int n_in,
                              void* d_out, int out_size, void* d_ws, size_t ws_size,
                              hipStream_t stream) {
    int ih = 0, isrc = 1, idst = 2, iW1s = 3, iW1d = 4, ial1 = 5, iar1 = 6,
        iW2s = 7, iW2d = 8, ial2 = 9, iar2 = 10, iWres = 11;
    if (n_in >= 12 && in_sizes[0] != 12800000) {
        iW1d = 0; iW1s = 1; iW2d = 2; iW2s = 3; iWres = 4; ial1 = 5; ial2 = 6;
        iar1 = 7; iar2 = 8; idst = 9; ih = 10; isrc = 11;
    }
    const void* h     = d_in[ih];
    const int* src    = (const int*)d_in[isrc];
    const int* dst    = (const int*)d_in[idst];
    const void* W1s   = d_in[iW1s];
    const void* W1d   = d_in[iW1d];
    const void* al1   = d_in[ial1];
    const void* ar1   = d_in[iar1];
    const void* W2s   = d_in[iW2s];
    const void* W2d   = d_in[iW2d];
    const void* al2   = d_in[ial2];
    const void* ar2   = d_in[iar2];
    const void* Wres2 = d_in[iWres];

    char* w = (char*)d_ws;
    size_t off = 0;
    auto alloc = [&](size_t bytes) -> void* {
        void* p = w + off;
        off += (bytes + 255) & ~(size_t)255;
        return p;
    };
    int* mode   = (int*)alloc(256);
    float* wl1 = (float*)alloc(256 * 4 * 4);
    float* wr1 = (float*)alloc(256 * 4 * 4);
    float* wl2 = (float*)alloc(256 * 4 * 4);
    float* wr2 = (float*)alloc(256 * 4 * 4);
    int* deg    = (int*)alloc(NN * 4);
    int* rowptr = (int*)alloc((NN + 1) * 4);
    int* bsum   = (int*)alloc(NBLK_SCAN * 4);
    int* eorder = (int*)alloc((size_t)EE * 4);
    int* csrc   = (int*)alloc((size_t)EE * 4);
    u16* aw     = (u16*)alloc((size_t)EE * 4 * 2);     // 6.8 MB (reused for layer 2)
    float* el1  = (float*)alloc((size_t)NN * 4 * 4);
    float* er1  = (float*)alloc((size_t)NN * 4 * 4);
    float* el2  = (float*)alloc((size_t)NN * 4 * 4);
    float* er2  = (float*)alloc((size_t)NN * 4 * 4);
    u16* BT1    = (u16*)alloc(256 * 256 * 2);
    u16* BT2    = (u16*)alloc(256 * 256 * 2);
    u16* fs1    = (u16*)alloc((size_t)NN * 256 * 2);   // 25.6 MB
    u16* hb     = (u16*)alloc((size_t)NN * 256 * 2);   // 25.6 MB: h bf16, then h1
    u16* c2     = fs1;   // fs1 dead after k_agg1; c2 = [fs2 | res2]

    // 1: detect + zero deg
    k_detect<<<197, 256, 0, stream>>>((const u16*)h, mode, deg);
    // 2: B-transpose + attn vecs + deg count + edge ranks
    k_prep<<<528 + (EE + 255) / 256, 256, 0, stream>>>(
        W1s, al1, W1d, ar1, W2s, al2, W2d, ar2, Wres2, dst,
        BT1, BT2, wl1, wr1, wl2, wr2, deg, eorder, mode);
    // 3: scan stage 1
    k_scan1<<<NBLK_SCAN, 512, 0, stream>>>(deg, rowptr, bsum);
    // 4: scan finalize + eler1 + h->bf16 (hb)
    k_scan3_eler1<<<196 + NN / 4, 256, 0, stream>>>(rowptr, bsum,
                                                    h, hb, wl1, wr1, el1, er1, mode);
    // 5: layer-1 weights + CSR scatter (atomic-free)
    k_awgen<<<(EE + 255) / 256, 256, 0, stream>>>(src, dst, eorder, rowptr,
                                                  el1, er1, aw, csrc, 1);
    // 6: layer-1 GEMM (A = hb bf16)
    k_gemm_mfma<<<782, 256, 0, stream>>>(hb, BT1, fs1);
    // 7: layer-1 aggregation + fused eler2 (hb: residual in, h1 out)
    k_agg1<<<NN / 4, 256, 0, stream>>>(rowptr, csrc, aw, fs1, hb,
                                       wl2, wr2, el2, er2);
    // 8: layer-2 fused GEMM [W2s | Wres2] (A = h1 in hb)
    k_gemm_mfma<<<782, 256, 0, stream>>>(hb, BT2, c2);
    // 9: layer-2 weights (atomic-free, aw buffer reused)
    k_awgen<<<(EE + 255) / 256, 256, 0, stream>>>(src, dst, eorder, rowptr,
                                                  el2, er2, aw, csrc, 0);
    // 10: layer-2 aggregation + residual + head-mean
    k_agg2<<<NN / 4, 256, 0, stream>>>(rowptr, csrc, aw, c2, d_out, mode);
}

// Round 6
// 381.177 us; speedup vs baseline: 1.0121x; 1.0121x over previous
//
#include <hip/hip_runtime.h>
#include <hip/hip_bf16.h>

#define NN 50000
#define EE 850000
#define NBLK_SCAN 98  // ceil(50000/512)

typedef unsigned short u16;
using short8 = __attribute__((ext_vector_type(8))) short;
using f32x4  = __attribute__((ext_vector_type(4))) float;

__device__ __forceinline__ float bf2f(u16 u) {
    union { unsigned int i; float f; } v; v.i = ((unsigned int)u) << 16; return v.f;
}
__device__ __forceinline__ u16 f2bf(float f) {
    __hip_bfloat16 h = __float2bfloat16(f);
    return *reinterpret_cast<u16*>(&h);
}

__device__ __forceinline__ float ld1(const void* X, size_t i, bool f32m) {
    return f32m ? ((const float*)X)[i] : bf2f(((const u16*)X)[i]);
}
__device__ __forceinline__ void load4(const void* X, size_t g, bool f32m, float o[4]) {
    if (f32m) {
        float4 v = ((const float4*)X)[g];
        o[0] = v.x; o[1] = v.y; o[2] = v.z; o[3] = v.w;
    } else {
        ushort4 v = ((const ushort4*)X)[g];
        o[0] = bf2f(v.x); o[1] = bf2f(v.y); o[2] = bf2f(v.z); o[3] = bf2f(v.w);
    }
}

// ---- block 0: dtype detect; blocks 1..196: zero deg ----
__global__ void k_detect(const u16* __restrict__ hh, int* __restrict__ flag,
                         int* __restrict__ deg) {
    if (blockIdx.x != 0) {
        int i = (blockIdx.x - 1) * 256 + threadIdx.x;
        if (i < NN) deg[i] = 0;
        return;
    }
    __shared__ int sm[256];
    int t = threadIdx.x;
    int c = 0;
    for (int i = 0; i < 16; ++i) {
        u16 u = hh[t * 16 + i];
        int e = (u >> 7) & 0xFF;
        if (e != 0 && (e < 90 || e > 160)) ++c;
    }
    sm[t] = c;
    __syncthreads();
    for (int s = 128; s > 0; s >>= 1) {
        if (t < s) sm[t] += sm[t + s];
        __syncthreads();
    }
    if (t == 0) *flag = (sm[0] > 200) ? 1 : 0;
}

// ---- fused prep: 0..511 B-transpose, 512..527 attn vecs, rest deg+rank ----
__global__ void k_prep(const void* __restrict__ W1s, const void* __restrict__ al1,
                       const void* __restrict__ W1d, const void* __restrict__ ar1,
                       const void* __restrict__ W2s, const void* __restrict__ al2,
                       const void* __restrict__ W2d, const void* __restrict__ ar2,
                       const void* __restrict__ Wres2, const int* __restrict__ dst,
                       u16* __restrict__ BT1, u16* __restrict__ BT2,
                       float* __restrict__ wl1, float* __restrict__ wr1,
                       float* __restrict__ wl2, float* __restrict__ wr2,
                       int* __restrict__ deg, int* __restrict__ eorder,
                       const int* __restrict__ mode) {
    int bid = blockIdx.x;
    if (bid >= 528) {
        int e = (bid - 528) * 256 + threadIdx.x;
        if (e < EE) {
            int r = atomicAdd(&deg[dst[e]], 1);
            eorder[e] = r;
        }
        return;
    }
    bool f32m = (*mode) != 0;
    if (bid < 512) {
        int id = bid * 256 + threadIdx.x;  // 0..131071
        int which = id >> 16;
        int rem = id & 65535;
        int n = rem >> 8, k = rem & 255;
        if (which == 0) {
            BT1[n * 256 + k] = f2bf(ld1(W1s, (size_t)k * 256 + n, f32m));
        } else {
            float v = (n < 128) ? ld1(W2s, (size_t)k * 128 + n, f32m)
                                : ld1(Wres2, (size_t)k * 128 + (n - 128), f32m);
            BT2[n * 256 + k] = f2bf(v);
        }
    } else {
        int id = (bid - 512) * 256 + threadIdx.x;  // 0..4095
        int which = id >> 10;
        int rem = id & 1023;
        int k = rem >> 2, h = rem & 3;
        float s = 0.f;
        if (which == 0) {
            for (int d = 0; d < 64; ++d) s += ld1(W1s, k * 256 + h * 64 + d, f32m) * ld1(al1, h * 64 + d, f32m);
            wl1[k * 4 + h] = s;
        } else if (which == 1) {
            for (int d = 0; d < 64; ++d) s += ld1(W1d, k * 256 + h * 64 + d, f32m) * ld1(ar1, h * 64 + d, f32m);
            wr1[k * 4 + h] = s;
        } else if (which == 2) {
            for (int d = 0; d < 32; ++d) s += ld1(W2s, k * 128 + h * 32 + d, f32m) * ld1(al2, h * 32 + d, f32m);
            wl2[k * 4 + h] = s;
        } else {
            for (int d = 0; d < 32; ++d) s += ld1(W2d, k * 128 + h * 32 + d, f32m) * ld1(ar2, h * 32 + d, f32m);
            wr2[k * 4 + h] = s;
        }
    }
}

// ---- CSR scan stage 1: per-block inclusive scan + block sums ----
__global__ void k_scan1(const int* __restrict__ deg, int* __restrict__ rowptr,
                        int* __restrict__ bsum) {
    __shared__ int sm[512];
    int t = threadIdx.x;
    int i = blockIdx.x * 512 + t;
    int v = (i < NN) ? deg[i] : 0;
    int x = v;
    sm[t] = x;
    __syncthreads();
    for (int off = 1; off < 512; off <<= 1) {
        int y = (t >= off) ? sm[t - off] : 0;
        __syncthreads();
        x += y;
        sm[t] = x;
        __syncthreads();
    }
    if (i < NN) rowptr[i] = x - v;
    if (t == 511) bsum[blockIdx.x] = x;
}

// ---- fused: blocks 0..195 scan-finalize; rest eler1 + h->bf16 conversion ----
__global__ void k_scan3_eler1(int* __restrict__ rowptr, const int* __restrict__ bsum,
                              const void* __restrict__ X, u16* __restrict__ hb,
                              const float* __restrict__ wl, const float* __restrict__ wr,
                              float* __restrict__ el, float* __restrict__ er,
                              const int* __restrict__ mode) {
    int bid = blockIdx.x;
    if (bid < 196) {
        __shared__ int sm[NBLK_SCAN];
        int t = threadIdx.x;
        if (t < NBLK_SCAN) sm[t] = bsum[t];
        __syncthreads();
        int g = bid >> 1;  // each block's 256 indices lie in one 512-group
        int pre = 0;
        for (int j = 0; j < g; ++j) pre += sm[j];  // LDS broadcast, uniform
        int i = bid * 256 + t;
        if (i < NN) {
            rowptr[i] += pre;
            if (i == 0) rowptr[NN] = EE;
        }
        return;
    }
    bool f32m = (*mode) != 0;
    int wave = threadIdx.x >> 6, lane = threadIdx.x & 63;
    int node = (bid - 196) * 4 + wave;
    float a[4];
    load4(X, (size_t)node * 64 + lane, f32m, a);
    // persist bf16 copy of h: feeds GEMM1 A-staging + agg1 residual
    ushort4 hv = {f2bf(a[0]), f2bf(a[1]), f2bf(a[2]), f2bf(a[3])};
    ((ushort4*)hb)[(size_t)node * 64 + lane] = hv;
    float accl[4] = {0, 0, 0, 0}, accr[4] = {0, 0, 0, 0};
    int k0 = lane * 4;
#pragma unroll
    for (int j = 0; j < 4; ++j) {
        float4 wlv = ((const float4*)wl)[k0 + j];
        float4 wrv = ((const float4*)wr)[k0 + j];
        accl[0] += a[j] * wlv.x; accl[1] += a[j] * wlv.y;
        accl[2] += a[j] * wlv.z; accl[3] += a[j] * wlv.w;
        accr[0] += a[j] * wrv.x; accr[1] += a[j] * wrv.y;
        accr[2] += a[j] * wrv.z; accr[3] += a[j] * wrv.w;
    }
#pragma unroll
    for (int off = 32; off > 0; off >>= 1) {
#pragma unroll
        for (int t = 0; t < 4; ++t) {
            accl[t] += __shfl_down(accl[t], off, 64);
            accr[t] += __shfl_down(accr[t], off, 64);
        }
    }
    if (lane == 0) {
        float4 vl = {accl[0], accl[1], accl[2], accl[3]};
        float4 vr = {accr[0], accr[1], accr[2], accr[3]};
        ((float4*)el)[node] = vl;
        ((float4*)er)[node] = vr;
    }
}

// ---- layer-1 weight gen: writes csrc + aw (agg1's preferred two-stream form) ----
__global__ void k_awgen1(const int* __restrict__ src, const int* __restrict__ dst,
                         const int* __restrict__ eorder, const int* __restrict__ rowptr,
                         const float* __restrict__ el, const float* __restrict__ er,
                         u16* __restrict__ aw, int* __restrict__ csrc) {
    int e = blockIdx.x * 256 + threadIdx.x;
    if (e >= EE) return;
    int s = src[e], d = dst[e];
    int slot = rowptr[d] + eorder[e];
    csrc[slot] = s;
    float4 eL = ((const float4*)el)[s];
    float4 eR = ((const float4*)er)[d];
    float ev[4] = {eL.x + eR.x, eL.y + eR.y, eL.z + eR.z, eL.w + eR.w};
    ushort4 o;
    u16* op = (u16*)&o;
#pragma unroll
    for (int t = 0; t < 4; ++t) {
        float x = ev[t];
        x = x > 0.f ? x : 0.2f * x;
        x = fminf(fmaxf(x, -60.f), 60.f);
        op[t] = f2bf(__expf(x));
    }
    ((ushort4*)aw)[slot] = o;
}

// ---- layer-2 weight gen: single packed 16B meta record (agg2's preferred form) ----
__global__ void k_awgen2(const int* __restrict__ src, const int* __restrict__ dst,
                         const int* __restrict__ eorder, const int* __restrict__ rowptr,
                         const float* __restrict__ el, const float* __restrict__ er,
                         uint4* __restrict__ meta) {
    int e = blockIdx.x * 256 + threadIdx.x;
    if (e >= EE) return;
    int s = src[e], d = dst[e];
    int slot = rowptr[d] + eorder[e];
    float4 eL = ((const float4*)el)[s];
    float4 eR = ((const float4*)er)[d];
    float ev[4] = {eL.x + eR.x, eL.y + eR.y, eL.z + eR.z, eL.w + eR.w};
    u16 op[4];
#pragma unroll
    for (int t = 0; t < 4; ++t) {
        float x = ev[t];
        x = x > 0.f ? x : 0.2f * x;
        x = fminf(fmaxf(x, -60.f), 60.f);
        op[t] = f2bf(__expf(x));
    }
    uint4 m;
    m.x = (unsigned int)s;
    m.y = (unsigned int)op[0] | ((unsigned int)op[1] << 16);
    m.z = (unsigned int)op[2] | ((unsigned int)op[3] << 16);
    m.w = 0u;
    meta[slot] = m;
}

// ---- MFMA GEMM: C[M][256] bf16 = A[M][256] @ B (BT transposed [256n][256k]) ----
// A always bf16 (hb). Epilogue restages C via swizzled LDS -> coalesced stores.
__global__ void k_gemm_mfma(const u16* __restrict__ A,
                            const u16* __restrict__ BT, u16* __restrict__ C) {
    __shared__ u16 smem[128 * 72 * 2];  // At|Bt, reused as Ct (32768 B)
    u16* At = smem;
    u16* Bt = smem + 128 * 72;
    int t = threadIdx.x;
    int lane = t & 63, w = t >> 6;
    int mt = blockIdx.x >> 1, nt = blockIdx.x & 1;
    int m0 = mt * 128, n0 = nt * 128;
    int wr = (w >> 1) * 64, wc = (w & 1) * 64;
    f32x4 acc[4][4] = {};
    int q = lane >> 4, cl = lane & 15;

    for (int ph = 0; ph < 4; ++ph) {
        int kb = ph * 64;
        for (int it = 0; it < 4; ++it) {
            int c = it * 256 + t;
            int row = c >> 3, c8 = c & 7;
            int rowg = m0 + row;
            float4 av;
            if (rowg < NN) {
                av = *(const float4*)(A + (size_t)rowg * 256 + kb + c8 * 8);
            } else {
                av = make_float4(0.f, 0.f, 0.f, 0.f);
            }
            *(float4*)&At[row * 72 + c8 * 8] = av;
            float4 bv = *(const float4*)(BT + (size_t)(n0 + row) * 256 + kb + c8 * 8);
            *(float4*)&Bt[row * 72 + c8 * 8] = bv;
        }
        __syncthreads();
#pragma unroll
        for (int ks = 0; ks < 2; ++ks) {
            short8 af[4], bf[4];
#pragma unroll
            for (int i = 0; i < 4; ++i)
                af[i] = *(const short8*)&At[(wr + i * 16 + cl) * 72 + ks * 32 + q * 8];
#pragma unroll
            for (int j = 0; j < 4; ++j)
                bf[j] = *(const short8*)&Bt[(wc + j * 16 + cl) * 72 + ks * 32 + q * 8];
#pragma unroll
            for (int i = 0; i < 4; ++i)
#pragma unroll
                for (int j = 0; j < 4; ++j)
                    acc[i][j] = __builtin_amdgcn_mfma_f32_16x16x32_bf16(af[i], bf[j], acc[i][j], 0, 0, 0);
        }
        __syncthreads();
    }
    // epilogue: acc -> swizzled LDS (conflict-free) -> coalesced dwordx4 stores
    u16* Ct = smem;
    int sw_w = q << 1;
#pragma unroll
    for (int i = 0; i < 4; ++i)
#pragma unroll
        for (int j = 0; j < 4; ++j) {
            int colb = wc + j * 16 + cl;
            int chunk = (colb >> 3) ^ sw_w;
#pragma unroll
            for (int r = 0; r < 4; ++r) {
                int row = wr + i * 16 + q * 4 + r;
                Ct[row * 128 + chunk * 8 + (colb & 7)] = f2bf(acc[i][j][r]);
            }
        }
    __syncthreads();
#pragma unroll
    for (int it = 0; it < 8; ++it) {
        int c = it * 256 + t;        // 0..2047 chunks of 16 B
        int row = c >> 4, k16 = c & 15;
        int mrow = m0 + row;
        if (mrow < NN) {
            int phys = k16 ^ (((row >> 2) & 3) << 1);
            float4 v = *(const float4*)&Ct[row * 128 + phys * 8];
            *(float4*)&C[(size_t)mrow * 256 + n0 + k16 * 8] = v;
        }
    }
}

// ---- layer-1 aggregation: weighted gather (csrc/aw streams) + bf16 residual + eler2 ----
// hb doubles as residual input and h1 output (same element, same thread).
__global__ void k_agg1(const int* __restrict__ rowptr, const int* __restrict__ csrc,
                       const u16* __restrict__ aw, const u16* __restrict__ fs,
                       u16* __restrict__ hb,
                       const float* __restrict__ wl2, const float* __restrict__ wr2,
                       float* __restrict__ el2, float* __restrict__ er2) {
    int wave = threadIdx.x >> 6, lane = threadIdx.x & 63;
    int node = blockIdx.x * 4 + wave;
    int beg = rowptr[node], end = rowptr[node + 1];
    int head = lane >> 4;
    float a0 = 0.f, a1 = 0.f, a2 = 0.f, a3 = 0.f, ll = 0.f;
#pragma unroll 8
    for (int p = beg; p < end; ++p) {
        int s = csrc[p];
        float pw = bf2f(aw[(size_t)p * 4 + head]);
        ushort4 fv = *(const ushort4*)(fs + (size_t)s * 256 + lane * 4);
        ll += pw;
        a0 += pw * bf2f(fv.x);
        a1 += pw * bf2f(fv.y);
        a2 += pw * bf2f(fv.z);
        a3 += pw * bf2f(fv.w);
    }
    float rinv = 1.f / ll;
    ushort4 rv = ((const ushort4*)hb)[(size_t)node * 64 + lane];
    float v0 = a0 * rinv + bf2f(rv.x), v1 = a1 * rinv + bf2f(rv.y);
    float v2 = a2 * rinv + bf2f(rv.z), v3 = a3 * rinv + bf2f(rv.w);
    v0 = v0 > 0.f ? v0 : __expf(v0) - 1.f;
    v1 = v1 > 0.f ? v1 : __expf(v1) - 1.f;
    v2 = v2 > 0.f ? v2 : __expf(v2) - 1.f;
    v3 = v3 > 0.f ? v3 : __expf(v3) - 1.f;
    ushort4 o = {f2bf(v0), f2bf(v1), f2bf(v2), f2bf(v3)};
    ((ushort4*)hb)[(size_t)node * 64 + lane] = o;
    // fused eler2: lane owns h1 cols lane*4..+3
    float4 w0 = ((const float4*)wl2)[lane * 4 + 0];
    float4 w1 = ((const float4*)wl2)[lane * 4 + 1];
    float4 w2 = ((const float4*)wl2)[lane * 4 + 2];
    float4 w3 = ((const float4*)wl2)[lane * 4 + 3];
    float4 r0 = ((const float4*)wr2)[lane * 4 + 0];
    float4 r1 = ((const float4*)wr2)[lane * 4 + 1];
    float4 r2 = ((const float4*)wr2)[lane * 4 + 2];
    float4 r3 = ((const float4*)wr2)[lane * 4 + 3];
    float acl[4], acr[4];
    acl[0] = v0 * w0.x + v1 * w1.x + v2 * w2.x + v3 * w3.x;
    acl[1] = v0 * w0.y + v1 * w1.y + v2 * w2.y + v3 * w3.y;
    acl[2] = v0 * w0.z + v1 * w1.z + v2 * w2.z + v3 * w3.z;
    acl[3] = v0 * w0.w + v1 * w1.w + v2 * w2.w + v3 * w3.w;
    acr[0] = v0 * r0.x + v1 * r1.x + v2 * r2.x + v3 * r3.x;
    acr[1] = v0 * r0.y + v1 * r1.y + v2 * r2.y + v3 * r3.y;
    acr[2] = v0 * r0.z + v1 * r1.z + v2 * r2.z + v3 * r3.z;
    acr[3] = v0 * r0.w + v1 * r1.w + v2 * r2.w + v3 * r3.w;
#pragma unroll
    for (int off = 32; off > 0; off >>= 1) {
#pragma unroll
        for (int t = 0; t < 4; ++t) {
            acl[t] += __shfl_down(acl[t], off, 64);
            acr[t] += __shfl_down(acr[t], off, 64);
        }
    }
    if (lane == 0) {
        float4 vl = {acl[0], acl[1], acl[2], acl[3]};
        float4 vr = {acr[0], acr[1], acr[2], acr[3]};
        ((float4*)el2)[node] = vl;
        ((float4*)er2)[node] = vr;
    }
}

// ---- layer-2 aggregation: weighted gather (meta single-stream) + residual + head-mean ----
__global__ void k_agg2(const int* __restrict__ rowptr, const uint4* __restrict__ meta,
                       const u16* __restrict__ c2,
                       void* __restrict__ out, const int* __restrict__ mode) {
    bool f32m = (*mode) != 0;
    int wave = threadIdx.x >> 6, lane = threadIdx.x & 63;
    int node = blockIdx.x * 4 + wave;
    int beg = rowptr[node], end = rowptr[node + 1];
    int head = lane >> 4;
    int hs2 = head & 2, hs1 = head & 1;
    float a0 = 0.f, a1 = 0.f, ll = 0.f;
#pragma unroll 8
    for (int p = beg; p < end; ++p) {
        uint4 mv = meta[p];
        int s = (int)mv.x;
        unsigned int wp = hs2 ? mv.z : mv.y;
        float pw = bf2f(hs1 ? (u16)(wp >> 16) : (u16)wp);
        ushort2 fv = *(const ushort2*)(c2 + (size_t)s * 256 + lane * 2);
        ll += pw;
        a0 += pw * bf2f(fv.x);
        a1 += pw * bf2f(fv.y);
    }
    float rinv = 1.f / ll;
    ushort2 rv = *(const ushort2*)(c2 + (size_t)node * 256 + 128 + lane * 2);
    float o0 = a0 * rinv + bf2f(rv.x);
    float o1 = a1 * rinv + bf2f(rv.y);
    o0 += __shfl_xor(o0, 16, 64); o0 += __shfl_xor(o0, 32, 64);
    o1 += __shfl_xor(o1, 16, 64); o1 += __shfl_xor(o1, 32, 64);
    if (lane < 16) {
        float v0 = 0.25f * o0, v1 = 0.25f * o1;
        size_t oi = (size_t)node * 32 + lane * 2;
        if (f32m) {
            ((float*)out)[oi] = v0;
            ((float*)out)[oi + 1] = v1;
        } else {
            ushort2 ov = {f2bf(v0), f2bf(v1)};
            *(ushort2*)((u16*)out + oi) = ov;
        }
    }
}

extern "C" void kernel_launch(void* const* d_in, const int* in_sizes, int n_in,
                              void* d_out, int out_size, void* d_ws, size_t ws_size,
                              hipStream_t stream) {
    int ih = 0, isrc = 1, idst = 2, iW1s = 3, iW1d = 4, ial1 = 5, iar1 = 6,
        iW2s = 7, iW2d = 8, ial2 = 9, iar2 = 10, iWres = 11;
    if (n_in >= 12 && in_sizes[0] != 12800000) {
        iW1d = 0; iW1s = 1; iW2d = 2; iW2s = 3; iWres = 4; ial1 = 5; ial2 = 6;
        iar1 = 7; iar2 = 8; idst = 9; ih = 10; isrc = 11;
    }
    const void* h     = d_in[ih];
    const int* src    = (const int*)d_in[isrc];
    const int* dst    = (const int*)d_in[idst];
    const void* W1s   = d_in[iW1s];
    const void* W1d   = d_in[iW1d];
    const void* al1   = d_in[ial1];
    const void* ar1   = d_in[iar1];
    const void* W2s   = d_in[iW2s];
    const void* W2d   = d_in[iW2d];
    const void* al2   = d_in[ial2];
    const void* ar2   = d_in[iar2];
    const void* Wres2 = d_in[iWres];

    char* w = (char*)d_ws;
    size_t off = 0;
    auto alloc = [&](size_t bytes) -> void* {
        void* p = w + off;
        off += (bytes + 255) & ~(size_t)255;
        return p;
    };
    int* mode   = (int*)alloc(256);
    float* wl1 = (float*)alloc(256 * 4 * 4);
    float* wr1 = (float*)alloc(256 * 4 * 4);
    float* wl2 = (float*)alloc(256 * 4 * 4);
    float* wr2 = (float*)alloc(256 * 4 * 4);
    int* deg    = (int*)alloc(NN * 4);
    int* rowptr = (int*)alloc((NN + 1) * 4);
    int* bsum   = (int*)alloc(NBLK_SCAN * 4);
    int* eorder = (int*)alloc((size_t)EE * 4);
    int* csrc   = (int*)alloc((size_t)EE * 4);
    u16* aw     = (u16*)alloc((size_t)EE * 4 * 2);     // 6.8 MB (layer-1)
    uint4* meta = (uint4*)alloc((size_t)EE * 16);      // 13.6 MB (layer-2)
    float* el1  = (float*)alloc((size_t)NN * 4 * 4);
    float* er1  = (float*)alloc((size_t)NN * 4 * 4);
    float* el2  = (float*)alloc((size_t)NN * 4 * 4);
    float* er2  = (float*)alloc((size_t)NN * 4 * 4);
    u16* BT1    = (u16*)alloc(256 * 256 * 2);
    u16* BT2    = (u16*)alloc(256 * 256 * 2);
    u16* fs1    = (u16*)alloc((size_t)NN * 256 * 2);   // 25.6 MB
    u16* hb     = (u16*)alloc((size_t)NN * 256 * 2);   // 25.6 MB: h bf16, then h1
    u16* c2     = fs1;   // fs1 dead after k_agg1; c2 = [fs2 | res2]

    // 1: detect + zero deg
    k_detect<<<197, 256, 0, stream>>>((const u16*)h, mode, deg);
    // 2: B-transpose + attn vecs + deg count + edge ranks
    k_prep<<<528 + (EE + 255) / 256, 256, 0, stream>>>(
        W1s, al1, W1d, ar1, W2s, al2, W2d, ar2, Wres2, dst,
        BT1, BT2, wl1, wr1, wl2, wr2, deg, eorder, mode);
    // 3: scan stage 1
    k_scan1<<<NBLK_SCAN, 512, 0, stream>>>(deg, rowptr, bsum);
    // 4: scan finalize + eler1 + h->bf16 (hb)
    k_scan3_eler1<<<196 + NN / 4, 256, 0, stream>>>(rowptr, bsum,
                                                    h, hb, wl1, wr1, el1, er1, mode);
    // 5: layer-1 weights + CSR scatter (csrc + aw streams)
    k_awgen1<<<(EE + 255) / 256, 256, 0, stream>>>(src, dst, eorder, rowptr,
                                                   el1, er1, aw, csrc);
    // 6: layer-1 GEMM (A = hb bf16)
    k_gemm_mfma<<<782, 256, 0, stream>>>(hb, BT1, fs1);
    // 7: layer-1 aggregation + fused eler2 (hb: residual in, h1 out)
    k_agg1<<<NN / 4, 256, 0, stream>>>(rowptr, csrc, aw, fs1, hb,
                                       wl2, wr2, el2, er2);
    // 8: layer-2 fused GEMM [W2s | Wres2] (A = h1 in hb)
    k_gemm_mfma<<<782, 256, 0, stream>>>(hb, BT2, c2);
    // 9: layer-2 weights -> packed meta (single 16B store)
    k_awgen2<<<(EE + 255) / 256, 256, 0, stream>>>(src, dst, eorder, rowptr,
                                                   el2, er2, meta);
    // 10: layer-2 aggregation + residual + head-mean
    k_agg2<<<NN / 4, 256, 0, stream>>>(rowptr, meta, c2, d_out, mode);
}

// Round 7
// 354.570 us; speedup vs baseline: 1.0881x; 1.0750x over previous
//
#include <hip/hip_runtime.h>
#include <hip/hip_bf16.h>

#define NN 50000
#define EE 850000
#define NBLK_SCAN 98  // ceil(50000/512)

typedef unsigned short u16;
using short8 = __attribute__((ext_vector_type(8))) short;
using f32x4  = __attribute__((ext_vector_type(4))) float;

__device__ __forceinline__ float bf2f(u16 u) {
    union { unsigned int i; float f; } v; v.i = ((unsigned int)u) << 16; return v.f;
}
__device__ __forceinline__ u16 f2bf(float f) {
    __hip_bfloat16 h = __float2bfloat16(f);
    return *reinterpret_cast<u16*>(&h);
}

__device__ __forceinline__ float ld1(const void* X, size_t i, bool f32m) {
    return f32m ? ((const float*)X)[i] : bf2f(((const u16*)X)[i]);
}
__device__ __forceinline__ void load4(const void* X, size_t g, bool f32m, float o[4]) {
    if (f32m) {
        float4 v = ((const float4*)X)[g];
        o[0] = v.x; o[1] = v.y; o[2] = v.z; o[3] = v.w;
    } else {
        ushort4 v = ((const ushort4*)X)[g];
        o[0] = bf2f(v.x); o[1] = bf2f(v.y); o[2] = bf2f(v.z); o[3] = bf2f(v.w);
    }
}

// ---- block 0: dtype detect; blocks 1..196: zero deg ----
__global__ void k_detect(const u16* __restrict__ hh, int* __restrict__ flag,
                         int* __restrict__ deg) {
    if (blockIdx.x != 0) {
        int i = (blockIdx.x - 1) * 256 + threadIdx.x;
        if (i < NN) deg[i] = 0;
        return;
    }
    __shared__ int sm[256];
    int t = threadIdx.x;
    int c = 0;
    for (int i = 0; i < 16; ++i) {
        u16 u = hh[t * 16 + i];
        int e = (u >> 7) & 0xFF;
        if (e != 0 && (e < 90 || e > 160)) ++c;
    }
    sm[t] = c;
    __syncthreads();
    for (int s = 128; s > 0; s >>= 1) {
        if (t < s) sm[t] += sm[t + s];
        __syncthreads();
    }
    if (t == 0) *flag = (sm[0] > 200) ? 1 : 0;
}

// ---- fused prep: 0..511 B-transpose, 512..527 attn vecs, rest deg+rank ----
__global__ void k_prep(const void* __restrict__ W1s, const void* __restrict__ al1,
                       const void* __restrict__ W1d, const void* __restrict__ ar1,
                       const void* __restrict__ W2s, const void* __restrict__ al2,
                       const void* __restrict__ W2d, const void* __restrict__ ar2,
                       const void* __restrict__ Wres2, const int* __restrict__ dst,
                       u16* __restrict__ BT1, u16* __restrict__ BT2,
                       float* __restrict__ wl1, float* __restrict__ wr1,
                       float* __restrict__ wl2, float* __restrict__ wr2,
                       int* __restrict__ deg, int* __restrict__ eorder,
                       const int* __restrict__ mode) {
    int bid = blockIdx.x;
    if (bid >= 528) {
        int e = (bid - 528) * 256 + threadIdx.x;
        if (e < EE) {
            int r = atomicAdd(&deg[dst[e]], 1);
            eorder[e] = r;
        }
        return;
    }
    bool f32m = (*mode) != 0;
    if (bid < 512) {
        int id = bid * 256 + threadIdx.x;  // 0..131071
        int which = id >> 16;
        int rem = id & 65535;
        int n = rem >> 8, k = rem & 255;
        if (which == 0) {
            BT1[n * 256 + k] = f2bf(ld1(W1s, (size_t)k * 256 + n, f32m));
        } else {
            float v = (n < 128) ? ld1(W2s, (size_t)k * 128 + n, f32m)
                                : ld1(Wres2, (size_t)k * 128 + (n - 128), f32m);
            BT2[n * 256 + k] = f2bf(v);
        }
    } else {
        int id = (bid - 512) * 256 + threadIdx.x;  // 0..4095
        int which = id >> 10;
        int rem = id & 1023;
        int k = rem >> 2, h = rem & 3;
        float s = 0.f;
        if (which == 0) {
            for (int d = 0; d < 64; ++d) s += ld1(W1s, k * 256 + h * 64 + d, f32m) * ld1(al1, h * 64 + d, f32m);
            wl1[k * 4 + h] = s;
        } else if (which == 1) {
            for (int d = 0; d < 64; ++d) s += ld1(W1d, k * 256 + h * 64 + d, f32m) * ld1(ar1, h * 64 + d, f32m);
            wr1[k * 4 + h] = s;
        } else if (which == 2) {
            for (int d = 0; d < 32; ++d) s += ld1(W2s, k * 128 + h * 32 + d, f32m) * ld1(al2, h * 32 + d, f32m);
            wl2[k * 4 + h] = s;
        } else {
            for (int d = 0; d < 32; ++d) s += ld1(W2d, k * 128 + h * 32 + d, f32m) * ld1(ar2, h * 32 + d, f32m);
            wr2[k * 4 + h] = s;
        }
    }
}

// ---- CSR scan stage 1: per-block inclusive scan + block sums ----
__global__ void k_scan1(const int* __restrict__ deg, int* __restrict__ rowptr,
                        int* __restrict__ bsum) {
    __shared__ int sm[512];
    int t = threadIdx.x;
    int i = blockIdx.x * 512 + t;
    int v = (i < NN) ? deg[i] : 0;
    int x = v;
    sm[t] = x;
    __syncthreads();
    for (int off = 1; off < 512; off <<= 1) {
        int y = (t >= off) ? sm[t - off] : 0;
        __syncthreads();
        x += y;
        sm[t] = x;
        __syncthreads();
    }
    if (i < NN) rowptr[i] = x - v;
    if (t == 511) bsum[blockIdx.x] = x;
}

// ---- fused: blocks 0..195 scan-finalize; rest eler1 + h->bf16 conversion ----
__global__ void k_scan3_eler1(int* __restrict__ rowptr, const int* __restrict__ bsum,
                              const void* __restrict__ X, u16* __restrict__ hb,
                              const float* __restrict__ wl, const float* __restrict__ wr,
                              float* __restrict__ el, float* __restrict__ er,
                              const int* __restrict__ mode) {
    int bid = blockIdx.x;
    if (bid < 196) {
        __shared__ int sm[NBLK_SCAN];
        int t = threadIdx.x;
        if (t < NBLK_SCAN) sm[t] = bsum[t];
        __syncthreads();
        int g = bid >> 1;  // each block's 256 indices lie in one 512-group
        int pre = 0;
        for (int j = 0; j < g; ++j) pre += sm[j];  // LDS broadcast, uniform
        int i = bid * 256 + t;
        if (i < NN) {
            rowptr[i] += pre;
            if (i == 0) rowptr[NN] = EE;
        }
        return;
    }
    bool f32m = (*mode) != 0;
    int wave = threadIdx.x >> 6, lane = threadIdx.x & 63;
    int node = (bid - 196) * 4 + wave;
    float a[4];
    load4(X, (size_t)node * 64 + lane, f32m, a);
    // persist bf16 copy of h: feeds GEMM1 A-staging + agg1 residual
    ushort4 hv = {f2bf(a[0]), f2bf(a[1]), f2bf(a[2]), f2bf(a[3])};
    ((ushort4*)hb)[(size_t)node * 64 + lane] = hv;
    float accl[4] = {0, 0, 0, 0}, accr[4] = {0, 0, 0, 0};
    int k0 = lane * 4;
#pragma unroll
    for (int j = 0; j < 4; ++j) {
        float4 wlv = ((const float4*)wl)[k0 + j];
        float4 wrv = ((const float4*)wr)[k0 + j];
        accl[0] += a[j] * wlv.x; accl[1] += a[j] * wlv.y;
        accl[2] += a[j] * wlv.z; accl[3] += a[j] * wlv.w;
        accr[0] += a[j] * wrv.x; accr[1] += a[j] * wrv.y;
        accr[2] += a[j] * wrv.z; accr[3] += a[j] * wrv.w;
    }
#pragma unroll
    for (int off = 32; off > 0; off >>= 1) {
#pragma unroll
        for (int t = 0; t < 4; ++t) {
            accl[t] += __shfl_down(accl[t], off, 64);
            accr[t] += __shfl_down(accr[t], off, 64);
        }
    }
    if (lane == 0) {
        float4 vl = {accl[0], accl[1], accl[2], accl[3]};
        float4 vr = {accr[0], accr[1], accr[2], accr[3]};
        ((float4*)el)[node] = vl;
        ((float4*)er)[node] = vr;
    }
}

// ---- layer-1 weight gen + CSR scatter: ONE packed 16B record per edge ----
// {src, w0|w1, w2|w3, 0}. Single scattered store (r4-measured fastest producer).
// Consumers read it with narrow loads (no uint4 unpack on their critical path).
__global__ void k_scatw(const int* __restrict__ src, const int* __restrict__ dst,
                        const int* __restrict__ eorder, const int* __restrict__ rowptr,
                        const float* __restrict__ el, const float* __restrict__ er,
                        uint4* __restrict__ meta) {
    int e = blockIdx.x * 256 + threadIdx.x;
    if (e >= EE) return;
    int s = src[e], d = dst[e];
    int slot = rowptr[d] + eorder[e];
    float4 eL = ((const float4*)el)[s];
    float4 eR = ((const float4*)er)[d];
    float ev[4] = {eL.x + eR.x, eL.y + eR.y, eL.z + eR.z, eL.w + eR.w};
    u16 op[4];
#pragma unroll
    for (int t = 0; t < 4; ++t) {
        float x = ev[t];
        x = x > 0.f ? x : 0.2f * x;
        x = fminf(fmaxf(x, -60.f), 60.f);
        op[t] = f2bf(__expf(x));
    }
    uint4 m;
    m.x = (unsigned int)s;
    m.y = (unsigned int)op[0] | ((unsigned int)op[1] << 16);
    m.z = (unsigned int)op[2] | ((unsigned int)op[3] << 16);
    m.w = 0u;
    meta[slot] = m;
}

// ---- MFMA GEMM: C[M][256] bf16 = A[M][256] @ B (BT transposed [256n][256k]) ----
// A always bf16 (hb). Epilogue restages C via swizzled LDS -> coalesced stores.
__global__ void k_gemm_mfma(const u16* __restrict__ A,
                            const u16* __restrict__ BT, u16* __restrict__ C) {
    __shared__ u16 smem[128 * 72 * 2];  // At|Bt, reused as Ct (32768 B)
    u16* At = smem;
    u16* Bt = smem + 128 * 72;
    int t = threadIdx.x;
    int lane = t & 63, w = t >> 6;
    int mt = blockIdx.x >> 1, nt = blockIdx.x & 1;
    int m0 = mt * 128, n0 = nt * 128;
    int wr = (w >> 1) * 64, wc = (w & 1) * 64;
    f32x4 acc[4][4] = {};
    int q = lane >> 4, cl = lane & 15;

    for (int ph = 0; ph < 4; ++ph) {
        int kb = ph * 64;
        for (int it = 0; it < 4; ++it) {
            int c = it * 256 + t;
            int row = c >> 3, c8 = c & 7;
            int rowg = m0 + row;
            float4 av;
            if (rowg < NN) {
                av = *(const float4*)(A + (size_t)rowg * 256 + kb + c8 * 8);
            } else {
                av = make_float4(0.f, 0.f, 0.f, 0.f);
            }
            *(float4*)&At[row * 72 + c8 * 8] = av;
            float4 bv = *(const float4*)(BT + (size_t)(n0 + row) * 256 + kb + c8 * 8);
            *(float4*)&Bt[row * 72 + c8 * 8] = bv;
        }
        __syncthreads();
#pragma unroll
        for (int ks = 0; ks < 2; ++ks) {
            short8 af[4], bf[4];
#pragma unroll
            for (int i = 0; i < 4; ++i)
                af[i] = *(const short8*)&At[(wr + i * 16 + cl) * 72 + ks * 32 + q * 8];
#pragma unroll
            for (int j = 0; j < 4; ++j)
                bf[j] = *(const short8*)&Bt[(wc + j * 16 + cl) * 72 + ks * 32 + q * 8];
#pragma unroll
            for (int i = 0; i < 4; ++i)
#pragma unroll
                for (int j = 0; j < 4; ++j)
                    acc[i][j] = __builtin_amdgcn_mfma_f32_16x16x32_bf16(af[i], bf[j], acc[i][j], 0, 0, 0);
        }
        __syncthreads();
    }
    // epilogue: acc -> swizzled LDS (conflict-free) -> coalesced dwordx4 stores
    u16* Ct = smem;
    int sw_w = q << 1;
#pragma unroll
    for (int i = 0; i < 4; ++i)
#pragma unroll
        for (int j = 0; j < 4; ++j) {
            int colb = wc + j * 16 + cl;
            int chunk = (colb >> 3) ^ sw_w;
#pragma unroll
            for (int r = 0; r < 4; ++r) {
                int row = wr + i * 16 + q * 4 + r;
                Ct[row * 128 + chunk * 8 + (colb & 7)] = f2bf(acc[i][j][r]);
            }
        }
    __syncthreads();
#pragma unroll
    for (int it = 0; it < 8; ++it) {
        int c = it * 256 + t;        // 0..2047 chunks of 16 B
        int row = c >> 4, k16 = c & 15;
        int mrow = m0 + row;
        if (mrow < NN) {
            int phys = k16 ^ (((row >> 2) & 3) << 1);
            float4 v = *(const float4*)&Ct[row * 128 + phys * 8];
            *(float4*)&C[(size_t)mrow * 256 + n0 + k16 * 8] = v;
        }
    }
}

// ---- layer-1 aggregation: weighted gather + bf16 residual + fused eler2 ----
// Reads meta via TWO NARROW loads (dword src + u16 weight, same 16B record ->
// same line): r5's proven low-pressure loop shape, r4's single-store producer.
__global__ void k_agg1(const int* __restrict__ rowptr, const uint4* __restrict__ meta,
                       const u16* __restrict__ fs, u16* __restrict__ hb,
                       const float* __restrict__ wl2, const float* __restrict__ wr2,
                       float* __restrict__ el2, float* __restrict__ er2) {
    int wave = threadIdx.x >> 6, lane = threadIdx.x & 63;
    int node = blockIdx.x * 4 + wave;
    int beg = rowptr[node], end = rowptr[node + 1];
    int head = lane >> 4;
    const int* ms = (const int*)meta;
    const u16* mw = (const u16*)meta + 2 + head;   // head's weight within record
    float a0 = 0.f, a1 = 0.f, a2 = 0.f, a3 = 0.f, ll = 0.f;
#pragma unroll 8
    for (int p = beg; p < end; ++p) {
        int s = ms[(size_t)p * 4];
        float pw = bf2f(mw[(size_t)p * 8]);
        ushort4 fv = *(const ushort4*)(fs + (size_t)s * 256 + lane * 4);
        ll += pw;
        a0 += pw * bf2f(fv.x);
        a1 += pw * bf2f(fv.y);
        a2 += pw * bf2f(fv.z);
        a3 += pw * bf2f(fv.w);
    }
    float rinv = 1.f / ll;
    ushort4 rv = ((const ushort4*)hb)[(size_t)node * 64 + lane];
    float v0 = a0 * rinv + bf2f(rv.x), v1 = a1 * rinv + bf2f(rv.y);
    float v2 = a2 * rinv + bf2f(rv.z), v3 = a3 * rinv + bf2f(rv.w);
    v0 = v0 > 0.f ? v0 : __expf(v0) - 1.f;
    v1 = v1 > 0.f ? v1 : __expf(v1) - 1.f;
    v2 = v2 > 0.f ? v2 : __expf(v2) - 1.f;
    v3 = v3 > 0.f ? v3 : __expf(v3) - 1.f;
    ushort4 o = {f2bf(v0), f2bf(v1), f2bf(v2), f2bf(v3)};
    ((ushort4*)hb)[(size_t)node * 64 + lane] = o;
    // fused eler2: lane owns h1 cols lane*4..+3
    float4 w0 = ((const float4*)wl2)[lane * 4 + 0];
    float4 w1 = ((const float4*)wl2)[lane * 4 + 1];
    float4 w2 = ((const float4*)wl2)[lane * 4 + 2];
    float4 w3 = ((const float4*)wl2)[lane * 4 + 3];
    float4 r0 = ((const float4*)wr2)[lane * 4 + 0];
    float4 r1 = ((const float4*)wr2)[lane * 4 + 1];
    float4 r2 = ((const float4*)wr2)[lane * 4 + 2];
    float4 r3 = ((const float4*)wr2)[lane * 4 + 3];
    float acl[4], acr[4];
    acl[0] = v0 * w0.x + v1 * w1.x + v2 * w2.x + v3 * w3.x;
    acl[1] = v0 * w0.y + v1 * w1.y + v2 * w2.y + v3 * w3.y;
    acl[2] = v0 * w0.z + v1 * w1.z + v2 * w2.z + v3 * w3.z;
    acl[3] = v0 * w0.w + v1 * w1.w + v2 * w2.w + v3 * w3.w;
    acr[0] = v0 * r0.x + v1 * r1.x + v2 * r2.x + v3 * r3.x;
    acr[1] = v0 * r0.y + v1 * r1.y + v2 * r2.y + v3 * r3.y;
    acr[2] = v0 * r0.z + v1 * r1.z + v2 * r2.z + v3 * r3.z;
    acr[3] = v0 * r0.w + v1 * r1.w + v2 * r2.w + v3 * r3.w;
#pragma unroll
    for (int off = 32; off > 0; off >>= 1) {
#pragma unroll
        for (int t = 0; t < 4; ++t) {
            acl[t] += __shfl_down(acl[t], off, 64);
            acr[t] += __shfl_down(acr[t], off, 64);
        }
    }
    if (lane == 0) {
        float4 vl = {acl[0], acl[1], acl[2], acl[3]};
        float4 vr = {acr[0], acr[1], acr[2], acr[3]};
        ((float4*)el2)[node] = vl;
        ((float4*)er2)[node] = vr;
    }
}

// ---- layer-2 aggregation: inline weight compute (awgen2 eliminated) ----
// src from meta (narrow dword); pw = exp(clamp(lrelu(el2[s][h] + er2[node][h])))
// computed in-loop: el2 is an 800KB L2-resident table, er2 term loop-invariant.
__global__ void k_agg2(const int* __restrict__ rowptr, const uint4* __restrict__ meta,
                       const float* __restrict__ el2, const float* __restrict__ er2,
                       const u16* __restrict__ c2,
                       void* __restrict__ out, const int* __restrict__ mode) {
    bool f32m = (*mode) != 0;
    int wave = threadIdx.x >> 6, lane = threadIdx.x & 63;
    int node = blockIdx.x * 4 + wave;
    int beg = rowptr[node], end = rowptr[node + 1];
    int head = lane >> 4;
    const int* ms = (const int*)meta;
    float erh = er2[node * 4 + head];
    float a0 = 0.f, a1 = 0.f, ll = 0.f;
#pragma unroll 8
    for (int p = beg; p < end; ++p) {
        int s = ms[(size_t)p * 4];
        float x = el2[s * 4 + head] + erh;
        x = x > 0.f ? x : 0.2f * x;
        x = fminf(fmaxf(x, -60.f), 60.f);
        float pw = __expf(x);
        ushort2 fv = *(const ushort2*)(c2 + (size_t)s * 256 + lane * 2);
        ll += pw;
        a0 += pw * bf2f(fv.x);
        a1 += pw * bf2f(fv.y);
    }
    float rinv = 1.f / ll;
    ushort2 rv = *(const ushort2*)(c2 + (size_t)node * 256 + 128 + lane * 2);
    float o0 = a0 * rinv + bf2f(rv.x);
    float o1 = a1 * rinv + bf2f(rv.y);
    o0 += __shfl_xor(o0, 16, 64); o0 += __shfl_xor(o0, 32, 64);
    o1 += __shfl_xor(o1, 16, 64); o1 += __shfl_xor(o1, 32, 64);
    if (lane < 16) {
        float v0 = 0.25f * o0, v1 = 0.25f * o1;
        size_t oi = (size_t)node * 32 + lane * 2;
        if (f32m) {
            ((float*)out)[oi] = v0;
            ((float*)out)[oi + 1] = v1;
        } else {
            ushort2 ov = {f2bf(v0), f2bf(v1)};
            *(ushort2*)((u16*)out + oi) = ov;
        }
    }
}

extern "C" void kernel_launch(void* const* d_in, const int* in_sizes, int n_in,
                              void* d_out, int out_size, void* d_ws, size_t ws_size,
                              hipStream_t stream) {
    int ih = 0, isrc = 1, idst = 2, iW1s = 3, iW1d = 4, ial1 = 5, iar1 = 6,
        iW2s = 7, iW2d = 8, ial2 = 9, iar2 = 10, iWres = 11;
    if (n_in >= 12 && in_sizes[0] != 12800000) {
        iW1d = 0; iW1s = 1; iW2d = 2; iW2s = 3; iWres = 4; ial1 = 5; ial2 = 6;
        iar1 = 7; iar2 = 8; idst = 9; ih = 10; isrc = 11;
    }
    const void* h     = d_in[ih];
    const int* src    = (const int*)d_in[isrc];
    const int* dst    = (const int*)d_in[idst];
    const void* W1s   = d_in[iW1s];
    const void* W1d   = d_in[iW1d];
    const void* al1   = d_in[ial1];
    const void* ar1   = d_in[iar1];
    const void* W2s   = d_in[iW2s];
    const void* W2d   = d_in[iW2d];
    const void* al2   = d_in[ial2];
    const void* ar2   = d_in[iar2];
    const void* Wres2 = d_in[iWres];

    char* w = (char*)d_ws;
    size_t off = 0;
    auto alloc = [&](size_t bytes) -> void* {
        void* p = w + off;
        off += (bytes + 255) & ~(size_t)255;
        return p;
    };
    int* mode   = (int*)alloc(256);
    float* wl1 = (float*)alloc(256 * 4 * 4);
    float* wr1 = (float*)alloc(256 * 4 * 4);
    float* wl2 = (float*)alloc(256 * 4 * 4);
    float* wr2 = (float*)alloc(256 * 4 * 4);
    int* deg    = (int*)alloc(NN * 4);
    int* rowptr = (int*)alloc((NN + 1) * 4);
    int* bsum   = (int*)alloc(NBLK_SCAN * 4);
    int* eorder = (int*)alloc((size_t)EE * 4);
    uint4* meta = (uint4*)alloc((size_t)EE * 16);      // 13.6 MB {src, w01, w23, 0}
    float* el1  = (float*)alloc((size_t)NN * 4 * 4);
    float* er1  = (float*)alloc((size_t)NN * 4 * 4);
    float* el2  = (float*)alloc((size_t)NN * 4 * 4);
    float* er2  = (float*)alloc((size_t)NN * 4 * 4);
    u16* BT1    = (u16*)alloc(256 * 256 * 2);
    u16* BT2    = (u16*)alloc(256 * 256 * 2);
    u16* fs1    = (u16*)alloc((size_t)NN * 256 * 2);   // 25.6 MB
    u16* hb     = (u16*)alloc((size_t)NN * 256 * 2);   // 25.6 MB: h bf16, then h1
    u16* c2     = fs1;   // fs1 dead after k_agg1; c2 = [fs2 | res2]

    // 1: detect + zero deg
    k_detect<<<197, 256, 0, stream>>>((const u16*)h, mode, deg);
    // 2: B-transpose + attn vecs + deg count + edge ranks
    k_prep<<<528 + (EE + 255) / 256, 256, 0, stream>>>(
        W1s, al1, W1d, ar1, W2s, al2, W2d, ar2, Wres2, dst,
        BT1, BT2, wl1, wr1, wl2, wr2, deg, eorder, mode);
    // 3: scan stage 1
    k_scan1<<<NBLK_SCAN, 512, 0, stream>>>(deg, rowptr, bsum);
    // 4: scan finalize + eler1 + h->bf16 (hb)
    k_scan3_eler1<<<196 + NN / 4, 256, 0, stream>>>(rowptr, bsum,
                                                    h, hb, wl1, wr1, el1, er1, mode);
    // 5: layer-1 weights + CSR scatter -> single packed meta record
    k_scatw<<<(EE + 255) / 256, 256, 0, stream>>>(src, dst, eorder, rowptr,
                                                  el1, er1, meta);
    // 6: layer-1 GEMM (A = hb bf16)
    k_gemm_mfma<<<782, 256, 0, stream>>>(hb, BT1, fs1);
    // 7: layer-1 aggregation + fused eler2 (hb: residual in, h1 out)
    k_agg1<<<NN / 4, 256, 0, stream>>>(rowptr, meta, fs1, hb,
                                       wl2, wr2, el2, er2);
    // 8: layer-2 fused GEMM [W2s | Wres2] (A = h1 in hb)
    k_gemm_mfma<<<782, 256, 0, stream>>>(hb, BT2, c2);
    // 9: layer-2 aggregation, weights computed inline (awgen2 eliminated)
    k_agg2<<<NN / 4, 256, 0, stream>>>(rowptr, meta, el2, er2, c2, d_out, mode);
}

// Round 8
// 350.279 us; speedup vs baseline: 1.1014x; 1.0123x over previous
//
#include <hip/hip_runtime.h>
#include <hip/hip_bf16.h>

#define NN 50000
#define EE 850000
#define NBLK_SCAN 98  // ceil(50000/512)

typedef unsigned short u16;
using short8 = __attribute__((ext_vector_type(8))) short;
using f32x4  = __attribute__((ext_vector_type(4))) float;

__device__ __forceinline__ float bf2f(u16 u) {
    union { unsigned int i; float f; } v; v.i = ((unsigned int)u) << 16; return v.f;
}
__device__ __forceinline__ u16 f2bf(float f) {
    __hip_bfloat16 h = __float2bfloat16(f);
    return *reinterpret_cast<u16*>(&h);
}

__device__ __forceinline__ float ld1(const void* X, size_t i, bool f32m) {
    return f32m ? ((const float*)X)[i] : bf2f(((const u16*)X)[i]);
}
__device__ __forceinline__ void load4(const void* X, size_t g, bool f32m, float o[4]) {
    if (f32m) {
        float4 v = ((const float4*)X)[g];
        o[0] = v.x; o[1] = v.y; o[2] = v.z; o[3] = v.w;
    } else {
        ushort4 v = ((const ushort4*)X)[g];
        o[0] = bf2f(v.x); o[1] = bf2f(v.y); o[2] = bf2f(v.z); o[3] = bf2f(v.w);
    }
}

// async global->LDS, 16B per lane; dest must be wave-uniform base + lane*16
__device__ __forceinline__ void gload_lds16(const void* g, void* l) {
    __builtin_amdgcn_global_load_lds(
        (const __attribute__((address_space(1))) unsigned int*)g,
        (__attribute__((address_space(3))) unsigned int*)l, 16, 0, 0);
}

// ---- block 0: dtype detect; blocks 1..196: zero deg ----
__global__ void k_detect(const u16* __restrict__ hh, int* __restrict__ flag,
                         int* __restrict__ deg) {
    if (blockIdx.x != 0) {
        int i = (blockIdx.x - 1) * 256 + threadIdx.x;
        if (i < NN) deg[i] = 0;
        return;
    }
    __shared__ int sm[256];
    int t = threadIdx.x;
    int c = 0;
    for (int i = 0; i < 16; ++i) {
        u16 u = hh[t * 16 + i];
        int e = (u >> 7) & 0xFF;
        if (e != 0 && (e < 90 || e > 160)) ++c;
    }
    sm[t] = c;
    __syncthreads();
    for (int s = 128; s > 0; s >>= 1) {
        if (t < s) sm[t] += sm[t + s];
        __syncthreads();
    }
    if (t == 0) *flag = (sm[0] > 200) ? 1 : 0;
}

// ---- fused prep ----
// blocks 0..31: LDS-tiled 64x64 transposes (coalesced both sides)
//   0..15  -> BT1[n][k] = W1s[k][n]         (a = n-tile, b = k-tile)
//   16..31 -> BT2[n][k] = [W2s|Wres2][k][n]
// blocks 32..47: attn vec dot-products (4-wide vectorized)
// blocks >=48: deg count + edge ranks (atomic)
__global__ void k_prep(const void* __restrict__ W1s, const void* __restrict__ al1,
                       const void* __restrict__ W1d, const void* __restrict__ ar1,
                       const void* __restrict__ W2s, const void* __restrict__ al2,
                       const void* __restrict__ W2d, const void* __restrict__ ar2,
                       const void* __restrict__ Wres2, const int* __restrict__ dst,
                       u16* __restrict__ BT1, u16* __restrict__ BT2,
                       float* __restrict__ wl1, float* __restrict__ wr1,
                       float* __restrict__ wl2, float* __restrict__ wr2,
                       int* __restrict__ deg, int* __restrict__ eorder,
                       const int* __restrict__ mode) {
    int bid = blockIdx.x;
    if (bid >= 48) {
        int e = (bid - 48) * 256 + threadIdx.x;
        if (e < EE) {
            int r = atomicAdd(&deg[dst[e]], 1);
            eorder[e] = r;
        }
        return;
    }
    bool f32m = (*mode) != 0;
    if (bid < 32) {
        __shared__ float tile[64][65];
        int which = bid >> 4;       // 0: BT1, 1: BT2
        int a = (bid >> 2) & 3;     // n-tile
        int b = bid & 3;            // k-tile
        int r4 = threadIdx.x >> 6;  // 0..3
        int cc = threadIdx.x & 63;
#pragma unroll 4
        for (int pass = 0; pass < 16; ++pass) {
            int r = pass * 4 + r4;
            int k = b * 64 + r;
            int n = a * 64 + cc;
            float v;
            if (which == 0) {
                v = ld1(W1s, (size_t)k * 256 + n, f32m);
            } else {
                v = (n < 128) ? ld1(W2s, (size_t)k * 128 + n, f32m)
                              : ld1(Wres2, (size_t)k * 128 + (n - 128), f32m);
            }
            tile[r][cc] = v;
        }
        __syncthreads();
        u16* BT = which ? BT2 : BT1;
#pragma unroll 4
        for (int pass = 0; pass < 16; ++pass) {
            int nn = pass * 4 + r4;
            BT[(size_t)(a * 64 + nn) * 256 + b * 64 + cc] = f2bf(tile[cc][nn]);
        }
        return;
    }
    // attn vec blocks
    int id = (bid - 32) * 256 + threadIdx.x;  // 0..4095
    int which = id >> 10;
    int rem = id & 1023;
    int k = rem >> 2, hh = rem & 3;
    float s = 0.f;
    float av[4], wv[4];
    if (which == 0) {
        for (int j = 0; j < 16; ++j) {
            load4(W1s, (size_t)k * 64 + hh * 16 + j, f32m, av);
            load4(al1, hh * 16 + j, f32m, wv);
            s += av[0] * wv[0] + av[1] * wv[1] + av[2] * wv[2] + av[3] * wv[3];
        }
        wl1[k * 4 + hh] = s;
    } else if (which == 1) {
        for (int j = 0; j < 16; ++j) {
            load4(W1d, (size_t)k * 64 + hh * 16 + j, f32m, av);
            load4(ar1, hh * 16 + j, f32m, wv);
            s += av[0] * wv[0] + av[1] * wv[1] + av[2] * wv[2] + av[3] * wv[3];
        }
        wr1[k * 4 + hh] = s;
    } else if (which == 2) {
        for (int j = 0; j < 8; ++j) {
            load4(W2s, (size_t)k * 32 + hh * 8 + j, f32m, av);
            load4(al2, hh * 8 + j, f32m, wv);
            s += av[0] * wv[0] + av[1] * wv[1] + av[2] * wv[2] + av[3] * wv[3];
        }
        wl2[k * 4 + hh] = s;
    } else {
        for (int j = 0; j < 8; ++j) {
            load4(W2d, (size_t)k * 32 + hh * 8 + j, f32m, av);
            load4(ar2, hh * 8 + j, f32m, wv);
            s += av[0] * wv[0] + av[1] * wv[1] + av[2] * wv[2] + av[3] * wv[3];
        }
        wr2[k * 4 + hh] = s;
    }
}

// ---- CSR scan stage 1: per-block inclusive scan + block sums ----
__global__ void k_scan1(const int* __restrict__ deg, int* __restrict__ rowptr,
                        int* __restrict__ bsum) {
    __shared__ int sm[512];
    int t = threadIdx.x;
    int i = blockIdx.x * 512 + t;
    int v = (i < NN) ? deg[i] : 0;
    int x = v;
    sm[t] = x;
    __syncthreads();
    for (int off = 1; off < 512; off <<= 1) {
        int y = (t >= off) ? sm[t - off] : 0;
        __syncthreads();
        x += y;
        sm[t] = x;
        __syncthreads();
    }
    if (i < NN) rowptr[i] = x - v;
    if (t == 511) bsum[blockIdx.x] = x;
}

// ---- fused: blocks 0..195 scan-finalize; rest eler1 + h->bf16 conversion ----
__global__ void k_scan3_eler1(int* __restrict__ rowptr, const int* __restrict__ bsum,
                              const void* __restrict__ X, u16* __restrict__ hb,
                              const float* __restrict__ wl, const float* __restrict__ wr,
                              float* __restrict__ el, float* __restrict__ er,
                              const int* __restrict__ mode) {
    int bid = blockIdx.x;
    if (bid < 196) {
        __shared__ int sm[NBLK_SCAN];
        int t = threadIdx.x;
        if (t < NBLK_SCAN) sm[t] = bsum[t];
        __syncthreads();
        int g = bid >> 1;  // each block's 256 indices lie in one 512-group
        int pre = 0;
        for (int j = 0; j < g; ++j) pre += sm[j];  // LDS broadcast, uniform
        int i = bid * 256 + t;
        if (i < NN) {
            rowptr[i] += pre;
            if (i == 0) rowptr[NN] = EE;
        }
        return;
    }
    bool f32m = (*mode) != 0;
    int wave = threadIdx.x >> 6, lane = threadIdx.x & 63;
    int node = (bid - 196) * 4 + wave;
    float a[4];
    load4(X, (size_t)node * 64 + lane, f32m, a);
    // persist bf16 copy of h: feeds GEMM1 A-staging + agg1 residual
    ushort4 hv = {f2bf(a[0]), f2bf(a[1]), f2bf(a[2]), f2bf(a[3])};
    ((ushort4*)hb)[(size_t)node * 64 + lane] = hv;
    float accl[4] = {0, 0, 0, 0}, accr[4] = {0, 0, 0, 0};
    int k0 = lane * 4;
#pragma unroll
    for (int j = 0; j < 4; ++j) {
        float4 wlv = ((const float4*)wl)[k0 + j];
        float4 wrv = ((const float4*)wr)[k0 + j];
        accl[0] += a[j] * wlv.x; accl[1] += a[j] * wlv.y;
        accl[2] += a[j] * wlv.z; accl[3] += a[j] * wlv.w;
        accr[0] += a[j] * wrv.x; accr[1] += a[j] * wrv.y;
        accr[2] += a[j] * wrv.z; accr[3] += a[j] * wrv.w;
    }
#pragma unroll
    for (int off = 32; off > 0; off >>= 1) {
#pragma unroll
        for (int t = 0; t < 4; ++t) {
            accl[t] += __shfl_down(accl[t], off, 64);
            accr[t] += __shfl_down(accr[t], off, 64);
        }
    }
    if (lane == 0) {
        float4 vl = {accl[0], accl[1], accl[2], accl[3]};
        float4 vr = {accr[0], accr[1], accr[2], accr[3]};
        ((float4*)el)[node] = vl;
        ((float4*)er)[node] = vr;
    }
}

// ---- layer-1 weight gen + CSR scatter: ONE packed 16B record per edge ----
__global__ void k_scatw(const int* __restrict__ src, const int* __restrict__ dst,
                        const int* __restrict__ eorder, const int* __restrict__ rowptr,
                        const float* __restrict__ el, const float* __restrict__ er,
                        uint4* __restrict__ meta) {
    int e = blockIdx.x * 256 + threadIdx.x;
    if (e >= EE) return;
    int s = src[e], d = dst[e];
    int slot = rowptr[d] + eorder[e];
    float4 eL = ((const float4*)el)[s];
    float4 eR = ((const float4*)er)[d];
    float ev[4] = {eL.x + eR.x, eL.y + eR.y, eL.z + eR.z, eL.w + eR.w};
    u16 op[4];
#pragma unroll
    for (int t = 0; t < 4; ++t) {
        float x = ev[t];
        x = x > 0.f ? x : 0.2f * x;
        x = fminf(fmaxf(x, -60.f), 60.f);
        op[t] = f2bf(__expf(x));
    }
    uint4 m;
    m.x = (unsigned int)s;
    m.y = (unsigned int)op[0] | ((unsigned int)op[1] << 16);
    m.z = (unsigned int)op[2] | ((unsigned int)op[3] << 16);
    m.w = 0u;
    meta[slot] = m;
}

// ---- MFMA GEMM: C[M][256] bf16 = A[M][256] @ B (BT transposed [256n][256k]) ----
// Staging via global_load_lds (16B/lane, async, no VGPR round-trip) into linear
// [row][64] LDS with XOR chunk swizzle (both-sides): source chunk pre-swizzled
// c8^(row&7); ds_read applies (4ks+q)^(cl&7). A rows beyond NN read garbage
// from the slack region (C store masks mrow<NN). Epilogue: swizzled Ct -> 
// coalesced dwordx4 stores.
__global__ void k_gemm_mfma(const u16* __restrict__ A,
                            const u16* __restrict__ BT, u16* __restrict__ C) {
    __shared__ u16 smem[16384];  // 32KB: At[128][64] | Bt[128][64], reused as Ct
    u16* At = smem;
    u16* Bt = smem + 8192;
    int t = threadIdx.x;
    int lane = t & 63, w = t >> 6;
    int mt = blockIdx.x >> 1, nt = blockIdx.x & 1;
    int m0 = mt * 128, n0 = nt * 128;
    int wr = (w >> 1) * 64, wc = (w & 1) * 64;
    f32x4 acc[4][4] = {};
    int q = lane >> 4, cl = lane & 15;
    int c7 = cl & 7;

    for (int ph = 0; ph < 4; ++ph) {
        int kb = ph * 64;
#pragma unroll
        for (int it = 0; it < 4; ++it) {
            int c = it * 256 + t;          // 16B chunk id 0..1023
            int row = c >> 3, c8 = c & 7;
            int sc8 = c8 ^ (row & 7);      // pre-swizzled source chunk
            gload_lds16(A + (size_t)(m0 + row) * 256 + kb + sc8 * 8, &At[c * 8]);
            gload_lds16(BT + (size_t)(n0 + row) * 256 + kb + sc8 * 8, &Bt[c * 8]);
        }
        __syncthreads();
#pragma unroll
        for (int ks = 0; ks < 2; ++ks) {
            short8 af[4], bf[4];
            int xa = ((ks * 4 + q) ^ c7) * 8;
#pragma unroll
            for (int i = 0; i < 4; ++i)
                af[i] = *(const short8*)&At[(wr + i * 16 + cl) * 64 + xa];
#pragma unroll
            for (int j = 0; j < 4; ++j)
                bf[j] = *(const short8*)&Bt[(wc + j * 16 + cl) * 64 + xa];
#pragma unroll
            for (int i = 0; i < 4; ++i)
#pragma unroll
                for (int j = 0; j < 4; ++j)
                    acc[i][j] = __builtin_amdgcn_mfma_f32_16x16x32_bf16(af[i], bf[j], acc[i][j], 0, 0, 0);
        }
        __syncthreads();
    }
    // epilogue: acc -> swizzled LDS (conflict-free) -> coalesced dwordx4 stores
    u16* Ct = smem;
    int sw_w = q << 1;
#pragma unroll
    for (int i = 0; i < 4; ++i)
#pragma unroll
        for (int j = 0; j < 4; ++j) {
            int colb = wc + j * 16 + cl;
            int chunk = (colb >> 3) ^ sw_w;
#pragma unroll
            for (int r = 0; r < 4; ++r) {
                int row = wr + i * 16 + q * 4 + r;
                Ct[row * 128 + chunk * 8 + (colb & 7)] = f2bf(acc[i][j][r]);
            }
        }
    __syncthreads();
#pragma unroll
    for (int it = 0; it < 8; ++it) {
        int c = it * 256 + t;        // 0..2047 chunks of 16 B
        int row = c >> 4, k16 = c & 15;
        int mrow = m0 + row;
        if (mrow < NN) {
            int phys = k16 ^ (((row >> 2) & 3) << 1);
            float4 v = *(const float4*)&Ct[row * 128 + phys * 8];
            *(float4*)&C[(size_t)mrow * 256 + n0 + k16 * 8] = v;
        }
    }
}

// ---- layer-1 aggregation: weighted gather + bf16 residual + fused eler2 ----
// Narrow meta reads (dword src + u16 weight, same 16B record -> same line).
__global__ void k_agg1(const int* __restrict__ rowptr, const uint4* __restrict__ meta,
                       const u16* __restrict__ fs, u16* __restrict__ hb,
                       const float* __restrict__ wl2, const float* __restrict__ wr2,
                       float* __restrict__ el2, float* __restrict__ er2) {
    int wave = threadIdx.x >> 6, lane = threadIdx.x & 63;
    int node = blockIdx.x * 4 + wave;
    int beg = rowptr[node], end = rowptr[node + 1];
    int head = lane >> 4;
    const int* ms = (const int*)meta;
    const u16* mw = (const u16*)meta + 2 + head;   // head's weight within record
    float a0 = 0.f, a1 = 0.f, a2 = 0.f, a3 = 0.f, ll = 0.f;
#pragma unroll 8
    for (int p = beg; p < end; ++p) {
        int s = ms[(size_t)p * 4];
        float pw = bf2f(mw[(size_t)p * 8]);
        ushort4 fv = *(const ushort4*)(fs + (size_t)s * 256 + lane * 4);
        ll += pw;
        a0 += pw * bf2f(fv.x);
        a1 += pw * bf2f(fv.y);
        a2 += pw * bf2f(fv.z);
        a3 += pw * bf2f(fv.w);
    }
    float rinv = 1.f / ll;
    ushort4 rv = ((const ushort4*)hb)[(size_t)node * 64 + lane];
    float v0 = a0 * rinv + bf2f(rv.x), v1 = a1 * rinv + bf2f(rv.y);
    float v2 = a2 * rinv + bf2f(rv.z), v3 = a3 * rinv + bf2f(rv.w);
    v0 = v0 > 0.f ? v0 : __expf(v0) - 1.f;
    v1 = v1 > 0.f ? v1 : __expf(v1) - 1.f;
    v2 = v2 > 0.f ? v2 : __expf(v2) - 1.f;
    v3 = v3 > 0.f ? v3 : __expf(v3) - 1.f;
    ushort4 o = {f2bf(v0), f2bf(v1), f2bf(v2), f2bf(v3)};
    ((ushort4*)hb)[(size_t)node * 64 + lane] = o;
    // fused eler2: lane owns h1 cols lane*4..+3
    float4 w0 = ((const float4*)wl2)[lane * 4 + 0];
    float4 w1 = ((const float4*)wl2)[lane * 4 + 1];
    float4 w2 = ((const float4*)wl2)[lane * 4 + 2];
    float4 w3 = ((const float4*)wl2)[lane * 4 + 3];
    float4 r0 = ((const float4*)wr2)[lane * 4 + 0];
    float4 r1 = ((const float4*)wr2)[lane * 4 + 1];
    float4 r2 = ((const float4*)wr2)[lane * 4 + 2];
    float4 r3 = ((const float4*)wr2)[lane * 4 + 3];
    float acl[4], acr[4];
    acl[0] = v0 * w0.x + v1 * w1.x + v2 * w2.x + v3 * w3.x;
    acl[1] = v0 * w0.y + v1 * w1.y + v2 * w2.y + v3 * w3.y;
    acl[2] = v0 * w0.z + v1 * w1.z + v2 * w2.z + v3 * w3.z;
    acl[3] = v0 * w0.w + v1 * w1.w + v2 * w2.w + v3 * w3.w;
    acr[0] = v0 * r0.x + v1 * r1.x + v2 * r2.x + v3 * r3.x;
    acr[1] = v0 * r0.y + v1 * r1.y + v2 * r2.y + v3 * r3.y;
    acr[2] = v0 * r0.z + v1 * r1.z + v2 * r2.z + v3 * r3.z;
    acr[3] = v0 * r0.w + v1 * r1.w + v2 * r2.w + v3 * r3.w;
#pragma unroll
    for (int off = 32; off > 0; off >>= 1) {
#pragma unroll
        for (int t = 0; t < 4; ++t) {
            acl[t] += __shfl_down(acl[t], off, 64);
            acr[t] += __shfl_down(acr[t], off, 64);
        }
    }
    if (lane == 0) {
        float4 vl = {acl[0], acl[1], acl[2], acl[3]};
        float4 vr = {acr[0], acr[1], acr[2], acr[3]};
        ((float4*)el2)[node] = vl;
        ((float4*)er2)[node] = vr;
    }
}

// ---- layer-2 aggregation: inline weight compute (no awgen2 pass) ----
__global__ void k_agg2(const int* __restrict__ rowptr, const uint4* __restrict__ meta,
                       const float* __restrict__ el2, const float* __restrict__ er2,
                       const u16* __restrict__ c2,
                       void* __restrict__ out, const int* __restrict__ mode) {
    bool f32m = (*mode) != 0;
    int wave = threadIdx.x >> 6, lane = threadIdx.x & 63;
    int node = blockIdx.x * 4 + wave;
    int beg = rowptr[node], end = rowptr[node + 1];
    int head = lane >> 4;
    const int* ms = (const int*)meta;
    float erh = er2[node * 4 + head];
    float a0 = 0.f, a1 = 0.f, ll = 0.f;
#pragma unroll 8
    for (int p = beg; p < end; ++p) {
        int s = ms[(size_t)p * 4];
        float x = el2[s * 4 + head] + erh;
        x = x > 0.f ? x : 0.2f * x;
        x = fminf(fmaxf(x, -60.f), 60.f);
        float pw = __expf(x);
        ushort2 fv = *(const ushort2*)(c2 + (size_t)s * 256 + lane * 2);
        ll += pw;
        a0 += pw * bf2f(fv.x);
        a1 += pw * bf2f(fv.y);
    }
    float rinv = 1.f / ll;
    ushort2 rv = *(const ushort2*)(c2 + (size_t)node * 256 + 128 + lane * 2);
    float o0 = a0 * rinv + bf2f(rv.x);
    float o1 = a1 * rinv + bf2f(rv.y);
    o0 += __shfl_xor(o0, 16, 64); o0 += __shfl_xor(o0, 32, 64);
    o1 += __shfl_xor(o1, 16, 64); o1 += __shfl_xor(o1, 32, 64);
    if (lane < 16) {
        float v0 = 0.25f * o0, v1 = 0.25f * o1;
        size_t oi = (size_t)node * 32 + lane * 2;
        if (f32m) {
            ((float*)out)[oi] = v0;
            ((float*)out)[oi + 1] = v1;
        } else {
            ushort2 ov = {f2bf(v0), f2bf(v1)};
            *(ushort2*)((u16*)out + oi) = ov;
        }
    }
}

extern "C" void kernel_launch(void* const* d_in, const int* in_sizes, int n_in,
                              void* d_out, int out_size, void* d_ws, size_t ws_size,
                              hipStream_t stream) {
    int ih = 0, isrc = 1, idst = 2, iW1s = 3, iW1d = 4, ial1 = 5, iar1 = 6,
        iW2s = 7, iW2d = 8, ial2 = 9, iar2 = 10, iWres = 11;
    if (n_in >= 12 && in_sizes[0] != 12800000) {
        iW1d = 0; iW1s = 1; iW2d = 2; iW2s = 3; iWres = 4; ial1 = 5; ial2 = 6;
        iar1 = 7; iar2 = 8; idst = 9; ih = 10; isrc = 11;
    }
    const void* h     = d_in[ih];
    const int* src    = (const int*)d_in[isrc];
    const int* dst    = (const int*)d_in[idst];
    const void* W1s   = d_in[iW1s];
    const void* W1d   = d_in[iW1d];
    const void* al1   = d_in[ial1];
    const void* ar1   = d_in[iar1];
    const void* W2s   = d_in[iW2s];
    const void* W2d   = d_in[iW2d];
    const void* al2   = d_in[ial2];
    const void* ar2   = d_in[iar2];
    const void* Wres2 = d_in[iWres];

    char* w = (char*)d_ws;
    size_t off = 0;
    auto alloc = [&](size_t bytes) -> void* {
        void* p = w + off;
        off += (bytes + 255) & ~(size_t)255;
        return p;
    };
    int* mode   = (int*)alloc(256);
    float* wl1 = (float*)alloc(256 * 4 * 4);
    float* wr1 = (float*)alloc(256 * 4 * 4);
    float* wl2 = (float*)alloc(256 * 4 * 4);
    float* wr2 = (float*)alloc(256 * 4 * 4);
    int* deg    = (int*)alloc(NN * 4);
    int* rowptr = (int*)alloc((NN + 1) * 4);
    int* bsum   = (int*)alloc(NBLK_SCAN * 4);
    int* eorder = (int*)alloc((size_t)EE * 4);
    uint4* meta = (uint4*)alloc((size_t)EE * 16);      // 13.6 MB {src, w01, w23, 0}
    float* el1  = (float*)alloc((size_t)NN * 4 * 4);
    float* er1  = (float*)alloc((size_t)NN * 4 * 4);
    float* el2  = (float*)alloc((size_t)NN * 4 * 4);
    float* er2  = (float*)alloc((size_t)NN * 4 * 4);
    u16* BT1    = (u16*)alloc(256 * 256 * 2);
    u16* BT2    = (u16*)alloc(256 * 256 * 2);
    u16* fs1    = (u16*)alloc((size_t)NN * 256 * 2);          // 25.6 MB
    u16* hb     = (u16*)alloc((size_t)(NN + 64) * 256 * 2);   // +64 rows slack (GEMM OOB tile reads)
    u16* c2     = fs1;   // fs1 dead after k_agg1; c2 = [fs2 | res2]

    // 1: detect + zero deg
    k_detect<<<197, 256, 0, stream>>>((const u16*)h, mode, deg);
    // 2: tiled B-transpose + attn vecs + deg count + edge ranks
    k_prep<<<48 + (EE + 255) / 256, 256, 0, stream>>>(
        W1s, al1, W1d, ar1, W2s, al2, W2d, ar2, Wres2, dst,
        BT1, BT2, wl1, wr1, wl2, wr2, deg, eorder, mode);
    // 3: scan stage 1
    k_scan1<<<NBLK_SCAN, 512, 0, stream>>>(deg, rowptr, bsum);
    // 4: scan finalize + eler1 + h->bf16 (hb)
    k_scan3_eler1<<<196 + NN / 4, 256, 0, stream>>>(rowptr, bsum,
                                                    h, hb, wl1, wr1, el1, er1, mode);
    // 5: layer-1 weights + CSR scatter -> single packed meta record
    k_scatw<<<(EE + 255) / 256, 256, 0, stream>>>(src, dst, eorder, rowptr,
                                                  el1, er1, meta);
    // 6: layer-1 GEMM (A = hb bf16, global_load_lds staging)
    k_gemm_mfma<<<782, 256, 0, stream>>>(hb, BT1, fs1);
    // 7: layer-1 aggregation + fused eler2 (hb: residual in, h1 out)
    k_agg1<<<NN / 4, 256, 0, stream>>>(rowptr, meta, fs1, hb,
                                       wl2, wr2, el2, er2);
    // 8: layer-2 fused GEMM [W2s | Wres2] (A = h1 in hb)
    k_gemm_mfma<<<782, 256, 0, stream>>>(hb, BT2, c2);
    // 9: layer-2 aggregation, weights computed inline
    k_agg2<<<NN / 4, 256, 0, stream>>>(rowptr, meta, el2, er2, c2, d_out, mode);
}

// Round 9
// 345.030 us; speedup vs baseline: 1.1181x; 1.0152x over previous
//
#include <hip/hip_runtime.h>
#include <hip/hip_bf16.h>

#define NN 50000
#define EE 850000
#define NBLK_SCAN 98  // ceil(50000/512)

typedef unsigned short u16;
using short8 = __attribute__((ext_vector_type(8))) short;
using f32x4  = __attribute__((ext_vector_type(4))) float;

__device__ __forceinline__ float bf2f(u16 u) {
    union { unsigned int i; float f; } v; v.i = ((unsigned int)u) << 16; return v.f;
}
__device__ __forceinline__ u16 f2bf(float f) {
    __hip_bfloat16 h = __float2bfloat16(f);
    return *reinterpret_cast<u16*>(&h);
}

__device__ __forceinline__ float ld1(const void* X, size_t i, bool f32m) {
    return f32m ? ((const float*)X)[i] : bf2f(((const u16*)X)[i]);
}
__device__ __forceinline__ void load4(const void* X, size_t g, bool f32m, float o[4]) {
    if (f32m) {
        float4 v = ((const float4*)X)[g];
        o[0] = v.x; o[1] = v.y; o[2] = v.z; o[3] = v.w;
    } else {
        ushort4 v = ((const ushort4*)X)[g];
        o[0] = bf2f(v.x); o[1] = bf2f(v.y); o[2] = bf2f(v.z); o[3] = bf2f(v.w);
    }
}

// async global->LDS, 16B per lane; dest must be wave-uniform base + lane*16
__device__ __forceinline__ void gload_lds16(const void* g, void* l) {
    __builtin_amdgcn_global_load_lds(
        (const __attribute__((address_space(1))) unsigned int*)g,
        (__attribute__((address_space(3))) unsigned int*)l, 16, 0, 0);
}

// ---- block 0: dtype detect; blocks 1..196: zero deg ----
__global__ void k_detect(const u16* __restrict__ hh, int* __restrict__ flag,
                         int* __restrict__ deg) {
    if (blockIdx.x != 0) {
        int i = (blockIdx.x - 1) * 256 + threadIdx.x;
        if (i < NN) deg[i] = 0;
        return;
    }
    __shared__ int sm[256];
    int t = threadIdx.x;
    int c = 0;
    for (int i = 0; i < 16; ++i) {
        u16 u = hh[t * 16 + i];
        int e = (u >> 7) & 0xFF;
        if (e != 0 && (e < 90 || e > 160)) ++c;
    }
    sm[t] = c;
    __syncthreads();
    for (int s = 128; s > 0; s >>= 1) {
        if (t < s) sm[t] += sm[t + s];
        __syncthreads();
    }
    if (t == 0) *flag = (sm[0] > 200) ? 1 : 0;
}

// ---- fused prep ----
// blocks 0..31: LDS-tiled 64x64 transposes (coalesced both sides)
// blocks 32..47: attn vec dot-products (4-wide vectorized)
// blocks >=48: deg count + edge ranks (atomic)
__global__ void k_prep(const void* __restrict__ W1s, const void* __restrict__ al1,
                       const void* __restrict__ W1d, const void* __restrict__ ar1,
                       const void* __restrict__ W2s, const void* __restrict__ al2,
                       const void* __restrict__ W2d, const void* __restrict__ ar2,
                       const void* __restrict__ Wres2, const int* __restrict__ dst,
                       u16* __restrict__ BT1, u16* __restrict__ BT2,
                       float* __restrict__ wl1, float* __restrict__ wr1,
                       float* __restrict__ wl2, float* __restrict__ wr2,
                       int* __restrict__ deg, int* __restrict__ eorder,
                       const int* __restrict__ mode) {
    int bid = blockIdx.x;
    if (bid >= 48) {
        int e = (bid - 48) * 256 + threadIdx.x;
        if (e < EE) {
            int r = atomicAdd(&deg[dst[e]], 1);
            eorder[e] = r;
        }
        return;
    }
    bool f32m = (*mode) != 0;
    if (bid < 32) {
        __shared__ float tile[64][65];
        int which = bid >> 4;       // 0: BT1, 1: BT2
        int a = (bid >> 2) & 3;     // n-tile
        int b = bid & 3;            // k-tile
        int r4 = threadIdx.x >> 6;  // 0..3
        int cc = threadIdx.x & 63;
#pragma unroll 4
        for (int pass = 0; pass < 16; ++pass) {
            int r = pass * 4 + r4;
            int k = b * 64 + r;
            int n = a * 64 + cc;
            float v;
            if (which == 0) {
                v = ld1(W1s, (size_t)k * 256 + n, f32m);
            } else {
                v = (n < 128) ? ld1(W2s, (size_t)k * 128 + n, f32m)
                              : ld1(Wres2, (size_t)k * 128 + (n - 128), f32m);
            }
            tile[r][cc] = v;
        }
        __syncthreads();
        u16* BT = which ? BT2 : BT1;
#pragma unroll 4
        for (int pass = 0; pass < 16; ++pass) {
            int nn = pass * 4 + r4;
            BT[(size_t)(a * 64 + nn) * 256 + b * 64 + cc] = f2bf(tile[cc][nn]);
        }
        return;
    }
    // attn vec blocks
    int id = (bid - 32) * 256 + threadIdx.x;  // 0..4095
    int which = id >> 10;
    int rem = id & 1023;
    int k = rem >> 2, hh = rem & 3;
    float s = 0.f;
    float av[4], wv[4];
    if (which == 0) {
        for (int j = 0; j < 16; ++j) {
            load4(W1s, (size_t)k * 64 + hh * 16 + j, f32m, av);
            load4(al1, hh * 16 + j, f32m, wv);
            s += av[0] * wv[0] + av[1] * wv[1] + av[2] * wv[2] + av[3] * wv[3];
        }
        wl1[k * 4 + hh] = s;
    } else if (which == 1) {
        for (int j = 0; j < 16; ++j) {
            load4(W1d, (size_t)k * 64 + hh * 16 + j, f32m, av);
            load4(ar1, hh * 16 + j, f32m, wv);
            s += av[0] * wv[0] + av[1] * wv[1] + av[2] * wv[2] + av[3] * wv[3];
        }
        wr1[k * 4 + hh] = s;
    } else if (which == 2) {
        for (int j = 0; j < 8; ++j) {
            load4(W2s, (size_t)k * 32 + hh * 8 + j, f32m, av);
            load4(al2, hh * 8 + j, f32m, wv);
            s += av[0] * wv[0] + av[1] * wv[1] + av[2] * wv[2] + av[3] * wv[3];
        }
        wl2[k * 4 + hh] = s;
    } else {
        for (int j = 0; j < 8; ++j) {
            load4(W2d, (size_t)k * 32 + hh * 8 + j, f32m, av);
            load4(ar2, hh * 8 + j, f32m, wv);
            s += av[0] * wv[0] + av[1] * wv[1] + av[2] * wv[2] + av[3] * wv[3];
        }
        wr2[k * 4 + hh] = s;
    }
}

// ---- CSR scan stage 1: per-block inclusive scan + block sums ----
__global__ void k_scan1(const int* __restrict__ deg, int* __restrict__ rowptr,
                        int* __restrict__ bsum) {
    __shared__ int sm[512];
    int t = threadIdx.x;
    int i = blockIdx.x * 512 + t;
    int v = (i < NN) ? deg[i] : 0;
    int x = v;
    sm[t] = x;
    __syncthreads();
    for (int off = 1; off < 512; off <<= 1) {
        int y = (t >= off) ? sm[t - off] : 0;
        __syncthreads();
        x += y;
        sm[t] = x;
        __syncthreads();
    }
    if (i < NN) rowptr[i] = x - v;
    if (t == 511) bsum[blockIdx.x] = x;
}

// ---- fused: blocks 0..195 scan-finalize; rest eler1 + h->bf16 conversion ----
__global__ void k_scan3_eler1(int* __restrict__ rowptr, const int* __restrict__ bsum,
                              const void* __restrict__ X, u16* __restrict__ hb,
                              const float* __restrict__ wl, const float* __restrict__ wr,
                              float* __restrict__ el, float* __restrict__ er,
                              const int* __restrict__ mode) {
    int bid = blockIdx.x;
    if (bid < 196) {
        __shared__ int sm[NBLK_SCAN];
        int t = threadIdx.x;
        if (t < NBLK_SCAN) sm[t] = bsum[t];
        __syncthreads();
        int g = bid >> 1;  // each block's 256 indices lie in one 512-group
        int pre = 0;
        for (int j = 0; j < g; ++j) pre += sm[j];  // LDS broadcast, uniform
        int i = bid * 256 + t;
        if (i < NN) {
            rowptr[i] += pre;
            if (i == 0) rowptr[NN] = EE;
        }
        return;
    }
    bool f32m = (*mode) != 0;
    int wave = threadIdx.x >> 6, lane = threadIdx.x & 63;
    int node = (bid - 196) * 4 + wave;
    float a[4];
    load4(X, (size_t)node * 64 + lane, f32m, a);
    // persist bf16 copy of h: feeds GEMM1 A-staging + agg1 residual
    ushort4 hv = {f2bf(a[0]), f2bf(a[1]), f2bf(a[2]), f2bf(a[3])};
    ((ushort4*)hb)[(size_t)node * 64 + lane] = hv;
    float accl[4] = {0, 0, 0, 0}, accr[4] = {0, 0, 0, 0};
    int k0 = lane * 4;
#pragma unroll
    for (int j = 0; j < 4; ++j) {
        float4 wlv = ((const float4*)wl)[k0 + j];
        float4 wrv = ((const float4*)wr)[k0 + j];
        accl[0] += a[j] * wlv.x; accl[1] += a[j] * wlv.y;
        accl[2] += a[j] * wlv.z; accl[3] += a[j] * wlv.w;
        accr[0] += a[j] * wrv.x; accr[1] += a[j] * wrv.y;
        accr[2] += a[j] * wrv.z; accr[3] += a[j] * wrv.w;
    }
#pragma unroll
    for (int off = 32; off > 0; off >>= 1) {
#pragma unroll
        for (int t = 0; t < 4; ++t) {
            accl[t] += __shfl_down(accl[t], off, 64);
            accr[t] += __shfl_down(accr[t], off, 64);
        }
    }
    if (lane == 0) {
        float4 vl = {accl[0], accl[1], accl[2], accl[3]};
        float4 vr = {accr[0], accr[1], accr[2], accr[3]};
        ((float4*)el)[node] = vl;
        ((float4*)er)[node] = vr;
    }
}

// ---- pure CSR scatter: csrc[rowptr[d]+eorder[e]] = src (weights now inline
// in the agg kernels; el/er gathers + exp removed from this pass) ----
__global__ void k_scat(const int* __restrict__ src, const int* __restrict__ dst,
                       const int* __restrict__ eorder, const int* __restrict__ rowptr,
                       int* __restrict__ csrc) {
    int e = blockIdx.x * 256 + threadIdx.x;
    if (e >= EE) return;
    csrc[rowptr[dst[e]] + eorder[e]] = src[e];
}

// ---- MFMA GEMM: C[M][256] bf16 = A[M][256] @ B (BT transposed [256n][256k]) ----
// Staging via global_load_lds (16B/lane, async) into linear [row][64] LDS with
// XOR chunk swizzle (both-sides). Epilogue: swizzled Ct -> coalesced stores.
__global__ void k_gemm_mfma(const u16* __restrict__ A,
                            const u16* __restrict__ BT, u16* __restrict__ C) {
    __shared__ u16 smem[16384];  // 32KB: At[128][64] | Bt[128][64], reused as Ct
    u16* At = smem;
    u16* Bt = smem + 8192;
    int t = threadIdx.x;
    int lane = t & 63, w = t >> 6;
    int mt = blockIdx.x >> 1, nt = blockIdx.x & 1;
    int m0 = mt * 128, n0 = nt * 128;
    int wr = (w >> 1) * 64, wc = (w & 1) * 64;
    f32x4 acc[4][4] = {};
    int q = lane >> 4, cl = lane & 15;
    int c7 = cl & 7;

    for (int ph = 0; ph < 4; ++ph) {
        int kb = ph * 64;
#pragma unroll
        for (int it = 0; it < 4; ++it) {
            int c = it * 256 + t;          // 16B chunk id 0..1023
            int row = c >> 3, c8 = c & 7;
            int sc8 = c8 ^ (row & 7);      // pre-swizzled source chunk
            gload_lds16(A + (size_t)(m0 + row) * 256 + kb + sc8 * 8, &At[c * 8]);
            gload_lds16(BT + (size_t)(n0 + row) * 256 + kb + sc8 * 8, &Bt[c * 8]);
        }
        __syncthreads();
#pragma unroll
        for (int ks = 0; ks < 2; ++ks) {
            short8 af[4], bf[4];
            int xa = ((ks * 4 + q) ^ c7) * 8;
#pragma unroll
            for (int i = 0; i < 4; ++i)
                af[i] = *(const short8*)&At[(wr + i * 16 + cl) * 64 + xa];
#pragma unroll
            for (int j = 0; j < 4; ++j)
                bf[j] = *(const short8*)&Bt[(wc + j * 16 + cl) * 64 + xa];
#pragma unroll
            for (int i = 0; i < 4; ++i)
#pragma unroll
                for (int j = 0; j < 4; ++j)
                    acc[i][j] = __builtin_amdgcn_mfma_f32_16x16x32_bf16(af[i], bf[j], acc[i][j], 0, 0, 0);
        }
        __syncthreads();
    }
    // epilogue: acc -> swizzled LDS (conflict-free) -> coalesced dwordx4 stores
    u16* Ct = smem;
    int sw_w = q << 1;
#pragma unroll
    for (int i = 0; i < 4; ++i)
#pragma unroll
        for (int j = 0; j < 4; ++j) {
            int colb = wc + j * 16 + cl;
            int chunk = (colb >> 3) ^ sw_w;
#pragma unroll
            for (int r = 0; r < 4; ++r) {
                int row = wr + i * 16 + q * 4 + r;
                Ct[row * 128 + chunk * 8 + (colb & 7)] = f2bf(acc[i][j][r]);
            }
        }
    __syncthreads();
#pragma unroll
    for (int it = 0; it < 8; ++it) {
        int c = it * 256 + t;        // 0..2047 chunks of 16 B
        int row = c >> 4, k16 = c & 15;
        int mrow = m0 + row;
        if (mrow < NN) {
            int phys = k16 ^ (((row >> 2) & 3) << 1);
            float4 v = *(const float4*)&Ct[row * 128 + phys * 8];
            *(float4*)&C[(size_t)mrow * 256 + n0 + k16 * 8] = v;
        }
    }
}

// ---- layer-1 aggregation: inline weights (el1 L2-gather + exp) + gather +
// bf16 residual + fused eler2. Mirrors agg2's proven r7 inline-weight loop. ----
__global__ void k_agg1(const int* __restrict__ rowptr, const int* __restrict__ csrc,
                       const float* __restrict__ el1, const float* __restrict__ er1,
                       const u16* __restrict__ fs, u16* __restrict__ hb,
                       const float* __restrict__ wl2, const float* __restrict__ wr2,
                       float* __restrict__ el2, float* __restrict__ er2) {
    int wave = threadIdx.x >> 6, lane = threadIdx.x & 63;
    int node = blockIdx.x * 4 + wave;
    int beg = rowptr[node], end = rowptr[node + 1];
    int head = lane >> 4;
    float erh = er1[node * 4 + head];
    float a0 = 0.f, a1 = 0.f, a2 = 0.f, a3 = 0.f, ll = 0.f;
#pragma unroll 8
    for (int p = beg; p < end; ++p) {
        int s = csrc[p];
        float x = el1[s * 4 + head] + erh;
        x = x > 0.f ? x : 0.2f * x;
        x = fminf(fmaxf(x, -60.f), 60.f);
        float pw = __expf(x);
        ushort4 fv = *(const ushort4*)(fs + (size_t)s * 256 + lane * 4);
        ll += pw;
        a0 += pw * bf2f(fv.x);
        a1 += pw * bf2f(fv.y);
        a2 += pw * bf2f(fv.z);
        a3 += pw * bf2f(fv.w);
    }
    float rinv = 1.f / ll;
    ushort4 rv = ((const ushort4*)hb)[(size_t)node * 64 + lane];
    float v0 = a0 * rinv + bf2f(rv.x), v1 = a1 * rinv + bf2f(rv.y);
    float v2 = a2 * rinv + bf2f(rv.z), v3 = a3 * rinv + bf2f(rv.w);
    v0 = v0 > 0.f ? v0 : __expf(v0) - 1.f;
    v1 = v1 > 0.f ? v1 : __expf(v1) - 1.f;
    v2 = v2 > 0.f ? v2 : __expf(v2) - 1.f;
    v3 = v3 > 0.f ? v3 : __expf(v3) - 1.f;
    ushort4 o = {f2bf(v0), f2bf(v1), f2bf(v2), f2bf(v3)};
    ((ushort4*)hb)[(size_t)node * 64 + lane] = o;
    // fused eler2: lane owns h1 cols lane*4..+3
    float4 w0 = ((const float4*)wl2)[lane * 4 + 0];
    float4 w1 = ((const float4*)wl2)[lane * 4 + 1];
    float4 w2 = ((const float4*)wl2)[lane * 4 + 2];
    float4 w3 = ((const float4*)wl2)[lane * 4 + 3];
    float4 r0 = ((const float4*)wr2)[lane * 4 + 0];
    float4 r1 = ((const float4*)wr2)[lane * 4 + 1];
    float4 r2 = ((const float4*)wr2)[lane * 4 + 2];
    float4 r3 = ((const float4*)wr2)[lane * 4 + 3];
    float acl[4], acr[4];
    acl[0] = v0 * w0.x + v1 * w1.x + v2 * w2.x + v3 * w3.x;
    acl[1] = v0 * w0.y + v1 * w1.y + v2 * w2.y + v3 * w3.y;
    acl[2] = v0 * w0.z + v1 * w1.z + v2 * w2.z + v3 * w3.z;
    acl[3] = v0 * w0.w + v1 * w1.w + v2 * w2.w + v3 * w3.w;
    acr[0] = v0 * r0.x + v1 * r1.x + v2 * r2.x + v3 * r3.x;
    acr[1] = v0 * r0.y + v1 * r1.y + v2 * r2.y + v3 * r3.y;
    acr[2] = v0 * r0.z + v1 * r1.z + v2 * r2.z + v3 * r3.z;
    acr[3] = v0 * r0.w + v1 * r1.w + v2 * r2.w + v3 * r3.w;
#pragma unroll
    for (int off = 32; off > 0; off >>= 1) {
#pragma unroll
        for (int t = 0; t < 4; ++t) {
            acl[t] += __shfl_down(acl[t], off, 64);
            acr[t] += __shfl_down(acr[t], off, 64);
        }
    }
    if (lane == 0) {
        float4 vl = {acl[0], acl[1], acl[2], acl[3]};
        float4 vr = {acr[0], acr[1], acr[2], acr[3]};
        ((float4*)el2)[node] = vl;
        ((float4*)er2)[node] = vr;
    }
}

// ---- layer-2 aggregation: inline weights + residual + head-mean ----
__global__ void k_agg2(const int* __restrict__ rowptr, const int* __restrict__ csrc,
                       const float* __restrict__ el2, const float* __restrict__ er2,
                       const u16* __restrict__ c2,
                       void* __restrict__ out, const int* __restrict__ mode) {
    bool f32m = (*mode) != 0;
    int wave = threadIdx.x >> 6, lane = threadIdx.x & 63;
    int node = blockIdx.x * 4 + wave;
    int beg = rowptr[node], end = rowptr[node + 1];
    int head = lane >> 4;
    float erh = er2[node * 4 + head];
    float a0 = 0.f, a1 = 0.f, ll = 0.f;
#pragma unroll 8
    for (int p = beg; p < end; ++p) {
        int s = csrc[p];
        float x = el2[s * 4 + head] + erh;
        x = x > 0.f ? x : 0.2f * x;
        x = fminf(fmaxf(x, -60.f), 60.f);
        float pw = __expf(x);
        ushort2 fv = *(const ushort2*)(c2 + (size_t)s * 256 + lane * 2);
        ll += pw;
        a0 += pw * bf2f(fv.x);
        a1 += pw * bf2f(fv.y);
    }
    float rinv = 1.f / ll;
    ushort2 rv = *(const ushort2*)(c2 + (size_t)node * 256 + 128 + lane * 2);
    float o0 = a0 * rinv + bf2f(rv.x);
    float o1 = a1 * rinv + bf2f(rv.y);
    o0 += __shfl_xor(o0, 16, 64); o0 += __shfl_xor(o0, 32, 64);
    o1 += __shfl_xor(o1, 16, 64); o1 += __shfl_xor(o1, 32, 64);
    if (lane < 16) {
        float v0 = 0.25f * o0, v1 = 0.25f * o1;
        size_t oi = (size_t)node * 32 + lane * 2;
        if (f32m) {
            ((float*)out)[oi] = v0;
            ((float*)out)[oi + 1] = v1;
        } else {
            ushort2 ov = {f2bf(v0), f2bf(v1)};
            *(ushort2*)((u16*)out + oi) = ov;
        }
    }
}

extern "C" void kernel_launch(void* const* d_in, const int* in_sizes, int n_in,
                              void* d_out, int out_size, void* d_ws, size_t ws_size,
                              hipStream_t stream) {
    int ih = 0, isrc = 1, idst = 2, iW1s = 3, iW1d = 4, ial1 = 5, iar1 = 6,
        iW2s = 7, iW2d = 8, ial2 = 9, iar2 = 10, iWres = 11;
    if (n_in >= 12 && in_sizes[0] != 12800000) {
        iW1d = 0; iW1s = 1; iW2d = 2; iW2s = 3; iWres = 4; ial1 = 5; ial2 = 6;
        iar1 = 7; iar2 = 8; idst = 9; ih = 10; isrc = 11;
    }
    const void* h     = d_in[ih];
    const int* src    = (const int*)d_in[isrc];
    const int* dst    = (const int*)d_in[idst];
    const void* W1s   = d_in[iW1s];
    const void* W1d   = d_in[iW1d];
    const void* al1   = d_in[ial1];
    const void* ar1   = d_in[iar1];
    const void* W2s   = d_in[iW2s];
    const void* W2d   = d_in[iW2d];
    const void* al2   = d_in[ial2];
    const void* ar2   = d_in[iar2];
    const void* Wres2 = d_in[iWres];

    char* w = (char*)d_ws;
    size_t off = 0;
    auto alloc = [&](size_t bytes) -> void* {
        void* p = w + off;
        off += (bytes + 255) & ~(size_t)255;
        return p;
    };
    int* mode   = (int*)alloc(256);
    float* wl1 = (float*)alloc(256 * 4 * 4);
    float* wr1 = (float*)alloc(256 * 4 * 4);
    float* wl2 = (float*)alloc(256 * 4 * 4);
    float* wr2 = (float*)alloc(256 * 4 * 4);
    int* deg    = (int*)alloc(NN * 4);
    int* rowptr = (int*)alloc((NN + 1) * 4);
    int* bsum   = (int*)alloc(NBLK_SCAN * 4);
    int* eorder = (int*)alloc((size_t)EE * 4);
    int* csrc   = (int*)alloc((size_t)EE * 4);         // 3.4 MB CSR src index
    float* el1  = (float*)alloc((size_t)NN * 4 * 4);
    float* er1  = (float*)alloc((size_t)NN * 4 * 4);
    float* el2  = (float*)alloc((size_t)NN * 4 * 4);
    float* er2  = (float*)alloc((size_t)NN * 4 * 4);
    u16* BT1    = (u16*)alloc(256 * 256 * 2);
    u16* BT2    = (u16*)alloc(256 * 256 * 2);
    u16* fs1    = (u16*)alloc((size_t)NN * 256 * 2);          // 25.6 MB
    u16* hb     = (u16*)alloc((size_t)(NN + 64) * 256 * 2);   // +64 rows slack (GEMM OOB tile reads)
    u16* c2     = fs1;   // fs1 dead after k_agg1; c2 = [fs2 | res2]

    // 1: detect + zero deg
    k_detect<<<197, 256, 0, stream>>>((const u16*)h, mode, deg);
    // 2: tiled B-transpose + attn vecs + deg count + edge ranks
    k_prep<<<48 + (EE + 255) / 256, 256, 0, stream>>>(
        W1s, al1, W1d, ar1, W2s, al2, W2d, ar2, Wres2, dst,
        BT1, BT2, wl1, wr1, wl2, wr2, deg, eorder, mode);
    // 3: scan stage 1
    k_scan1<<<NBLK_SCAN, 512, 0, stream>>>(deg, rowptr, bsum);
    // 4: scan finalize + eler1 + h->bf16 (hb)
    k_scan3_eler1<<<196 + NN / 4, 256, 0, stream>>>(rowptr, bsum,
                                                    h, hb, wl1, wr1, el1, er1, mode);
    // 5: pure CSR scatter (weights computed inline in agg kernels)
    k_scat<<<(EE + 255) / 256, 256, 0, stream>>>(src, dst, eorder, rowptr, csrc);
    // 6: layer-1 GEMM (A = hb bf16, global_load_lds staging)
    k_gemm_mfma<<<782, 256, 0, stream>>>(hb, BT1, fs1);
    // 7: layer-1 aggregation, inline weights + fused eler2 (hb: residual in, h1 out)
    k_agg1<<<NN / 4, 256, 0, stream>>>(rowptr, csrc, el1, er1, fs1, hb,
                                       wl2, wr2, el2, er2);
    // 8: layer-2 fused GEMM [W2s | Wres2] (A = h1 in hb)
    k_gemm_mfma<<<782, 256, 0, stream>>>(hb, BT2, c2);
    // 9: layer-2 aggregation, inline weights
    k_agg2<<<NN / 4, 256, 0, stream>>>(rowptr, csrc, el2, er2, c2, d_out, mode);
}

// Round 10
// 337.188 us; speedup vs baseline: 1.1442x; 1.0233x over previous
//
#include <hip/hip_runtime.h>
#include <hip/hip_bf16.h>

#define NN 50000
#define EE 850000
#define NBLK_SCAN 98  // ceil(50000/512)

typedef unsigned short u16;
using short8 = __attribute__((ext_vector_type(8))) short;
using f32x4  = __attribute__((ext_vector_type(4))) float;

__device__ __forceinline__ float bf2f(u16 u) {
    union { unsigned int i; float f; } v; v.i = ((unsigned int)u) << 16; return v.f;
}
__device__ __forceinline__ u16 f2bf(float f) {
    __hip_bfloat16 h = __float2bfloat16(f);
    return *reinterpret_cast<u16*>(&h);
}

__device__ __forceinline__ float ld1(const void* X, size_t i, bool f32m) {
    return f32m ? ((const float*)X)[i] : bf2f(((const u16*)X)[i]);
}
__device__ __forceinline__ void load4(const void* X, size_t g, bool f32m, float o[4]) {
    if (f32m) {
        float4 v = ((const float4*)X)[g];
        o[0] = v.x; o[1] = v.y; o[2] = v.z; o[3] = v.w;
    } else {
        ushort4 v = ((const ushort4*)X)[g];
        o[0] = bf2f(v.x); o[1] = bf2f(v.y); o[2] = bf2f(v.z); o[3] = bf2f(v.w);
    }
}

// async global->LDS, 16B per lane; dest must be wave-uniform base + lane*16
__device__ __forceinline__ void gload_lds16(const void* g, void* l) {
    __builtin_amdgcn_global_load_lds(
        (const __attribute__((address_space(1))) unsigned int*)g,
        (__attribute__((address_space(3))) unsigned int*)l, 16, 0, 0);
}

// ---- block 0: dtype detect; blocks 1..196: zero deg ----
__global__ void k_detect(const u16* __restrict__ hh, int* __restrict__ flag,
                         int* __restrict__ deg) {
    if (blockIdx.x != 0) {
        int i = (blockIdx.x - 1) * 256 + threadIdx.x;
        if (i < NN) deg[i] = 0;
        return;
    }
    __shared__ int sm[256];
    int t = threadIdx.x;
    int c = 0;
    for (int i = 0; i < 16; ++i) {
        u16 u = hh[t * 16 + i];
        int e = (u >> 7) & 0xFF;
        if (e != 0 && (e < 90 || e > 160)) ++c;
    }
    sm[t] = c;
    __syncthreads();
    for (int s = 128; s > 0; s >>= 1) {
        if (t < s) sm[t] += sm[t + s];
        __syncthreads();
    }
    if (t == 0) *flag = (sm[0] > 200) ? 1 : 0;
}

// ---- fused prep ----
// blocks 0..31: LDS-tiled 64x64 transposes (coalesced both sides)
// blocks 32..47: attn vec dot-products (4-wide vectorized)
// blocks >=48: deg count + edge ranks (atomic)
__global__ void k_prep(const void* __restrict__ W1s, const void* __restrict__ al1,
                       const void* __restrict__ W1d, const void* __restrict__ ar1,
                       const void* __restrict__ W2s, const void* __restrict__ al2,
                       const void* __restrict__ W2d, const void* __restrict__ ar2,
                       const void* __restrict__ Wres2, const int* __restrict__ dst,
                       u16* __restrict__ BT1, u16* __restrict__ BT2,
                       float* __restrict__ wl1, float* __restrict__ wr1,
                       float* __restrict__ wl2, float* __restrict__ wr2,
                       int* __restrict__ deg, int* __restrict__ eorder,
                       const int* __restrict__ mode) {
    int bid = blockIdx.x;
    if (bid >= 48) {
        int e = (bid - 48) * 256 + threadIdx.x;
        if (e < EE) {
            int r = atomicAdd(&deg[dst[e]], 1);
            eorder[e] = r;
        }
        return;
    }
    bool f32m = (*mode) != 0;
    if (bid < 32) {
        __shared__ float tile[64][65];
        int which = bid >> 4;       // 0: BT1, 1: BT2
        int a = (bid >> 2) & 3;     // n-tile
        int b = bid & 3;            // k-tile
        int r4 = threadIdx.x >> 6;  // 0..3
        int cc = threadIdx.x & 63;
#pragma unroll 4
        for (int pass = 0; pass < 16; ++pass) {
            int r = pass * 4 + r4;
            int k = b * 64 + r;
            int n = a * 64 + cc;
            float v;
            if (which == 0) {
                v = ld1(W1s, (size_t)k * 256 + n, f32m);
            } else {
                v = (n < 128) ? ld1(W2s, (size_t)k * 128 + n, f32m)
                              : ld1(Wres2, (size_t)k * 128 + (n - 128), f32m);
            }
            tile[r][cc] = v;
        }
        __syncthreads();
        u16* BT = which ? BT2 : BT1;
#pragma unroll 4
        for (int pass = 0; pass < 16; ++pass) {
            int nn = pass * 4 + r4;
            BT[(size_t)(a * 64 + nn) * 256 + b * 64 + cc] = f2bf(tile[cc][nn]);
        }
        return;
    }
    // attn vec blocks
    int id = (bid - 32) * 256 + threadIdx.x;  // 0..4095
    int which = id >> 10;
    int rem = id & 1023;
    int k = rem >> 2, hh = rem & 3;
    float s = 0.f;
    float av[4], wv[4];
    if (which == 0) {
        for (int j = 0; j < 16; ++j) {
            load4(W1s, (size_t)k * 64 + hh * 16 + j, f32m, av);
            load4(al1, hh * 16 + j, f32m, wv);
            s += av[0] * wv[0] + av[1] * wv[1] + av[2] * wv[2] + av[3] * wv[3];
        }
        wl1[k * 4 + hh] = s;
    } else if (which == 1) {
        for (int j = 0; j < 16; ++j) {
            load4(W1d, (size_t)k * 64 + hh * 16 + j, f32m, av);
            load4(ar1, hh * 16 + j, f32m, wv);
            s += av[0] * wv[0] + av[1] * wv[1] + av[2] * wv[2] + av[3] * wv[3];
        }
        wr1[k * 4 + hh] = s;
    } else if (which == 2) {
        for (int j = 0; j < 8; ++j) {
            load4(W2s, (size_t)k * 32 + hh * 8 + j, f32m, av);
            load4(al2, hh * 8 + j, f32m, wv);
            s += av[0] * wv[0] + av[1] * wv[1] + av[2] * wv[2] + av[3] * wv[3];
        }
        wl2[k * 4 + hh] = s;
    } else {
        for (int j = 0; j < 8; ++j) {
            load4(W2d, (size_t)k * 32 + hh * 8 + j, f32m, av);
            load4(ar2, hh * 8 + j, f32m, wv);
            s += av[0] * wv[0] + av[1] * wv[1] + av[2] * wv[2] + av[3] * wv[3];
        }
        wr2[k * 4 + hh] = s;
    }
}

// ---- CSR scan stage 1: per-block inclusive scan + block sums ----
__global__ void k_scan1(const int* __restrict__ deg, int* __restrict__ rowptr,
                        int* __restrict__ bsum) {
    __shared__ int sm[512];
    int t = threadIdx.x;
    int i = blockIdx.x * 512 + t;
    int v = (i < NN) ? deg[i] : 0;
    int x = v;
    sm[t] = x;
    __syncthreads();
    for (int off = 1; off < 512; off <<= 1) {
        int y = (t >= off) ? sm[t - off] : 0;
        __syncthreads();
        x += y;
        sm[t] = x;
        __syncthreads();
    }
    if (i < NN) rowptr[i] = x - v;
    if (t == 511) bsum[blockIdx.x] = x;
}

// ---- fused: blocks 0..195 scan-finalize; rest eler1 + h->bf16 conversion ----
// el1 emitted as PACKED BF16 table (el1b, 400KB: 2x line density for the agg1
// random probe); er1 stays f32 (node-local, loop-invariant in consumer).
__global__ void k_scan3_eler1(int* __restrict__ rowptr, const int* __restrict__ bsum,
                              const void* __restrict__ X, u16* __restrict__ hb,
                              const float* __restrict__ wl, const float* __restrict__ wr,
                              u16* __restrict__ el1b, float* __restrict__ er,
                              const int* __restrict__ mode) {
    int bid = blockIdx.x;
    if (bid < 196) {
        __shared__ int sm[NBLK_SCAN];
        int t = threadIdx.x;
        if (t < NBLK_SCAN) sm[t] = bsum[t];
        __syncthreads();
        int g = bid >> 1;  // each block's 256 indices lie in one 512-group
        int pre = 0;
        for (int j = 0; j < g; ++j) pre += sm[j];  // LDS broadcast, uniform
        int i = bid * 256 + t;
        if (i < NN) {
            rowptr[i] += pre;
            if (i == 0) rowptr[NN] = EE;
        }
        return;
    }
    bool f32m = (*mode) != 0;
    int wave = threadIdx.x >> 6, lane = threadIdx.x & 63;
    int node = (bid - 196) * 4 + wave;
    float a[4];
    load4(X, (size_t)node * 64 + lane, f32m, a);
    // persist bf16 copy of h: feeds GEMM1 A-staging + agg1 residual
    ushort4 hv = {f2bf(a[0]), f2bf(a[1]), f2bf(a[2]), f2bf(a[3])};
    ((ushort4*)hb)[(size_t)node * 64 + lane] = hv;
    float accl[4] = {0, 0, 0, 0}, accr[4] = {0, 0, 0, 0};
    int k0 = lane * 4;
#pragma unroll
    for (int j = 0; j < 4; ++j) {
        float4 wlv = ((const float4*)wl)[k0 + j];
        float4 wrv = ((const float4*)wr)[k0 + j];
        accl[0] += a[j] * wlv.x; accl[1] += a[j] * wlv.y;
        accl[2] += a[j] * wlv.z; accl[3] += a[j] * wlv.w;
        accr[0] += a[j] * wrv.x; accr[1] += a[j] * wrv.y;
        accr[2] += a[j] * wrv.z; accr[3] += a[j] * wrv.w;
    }
#pragma unroll
    for (int off = 32; off > 0; off >>= 1) {
#pragma unroll
        for (int t = 0; t < 4; ++t) {
            accl[t] += __shfl_down(accl[t], off, 64);
            accr[t] += __shfl_down(accr[t], off, 64);
        }
    }
    if (lane == 0) {
        ushort4 eb = {f2bf(accl[0]), f2bf(accl[1]), f2bf(accl[2]), f2bf(accl[3])};
        ((ushort4*)el1b)[node] = eb;
        float4 vr = {accr[0], accr[1], accr[2], accr[3]};
        ((float4*)er)[node] = vr;
    }
}

// ---- pure CSR scatter: csrc[rowptr[d]+eorder[e]] = src ----
__global__ void k_scat(const int* __restrict__ src, const int* __restrict__ dst,
                       const int* __restrict__ eorder, const int* __restrict__ rowptr,
                       int* __restrict__ csrc) {
    int e = blockIdx.x * 256 + threadIdx.x;
    if (e >= EE) return;
    csrc[rowptr[dst[e]] + eorder[e]] = src[e];
}

// ---- MFMA GEMM: C[M][256] bf16 = A[M][256] @ B (BT transposed [256n][256k]) ----
// Staging via global_load_lds (16B/lane, async) into linear [row][64] LDS with
// XOR chunk swizzle (both-sides). Epilogue: swizzled Ct -> coalesced stores.
__global__ void k_gemm_mfma(const u16* __restrict__ A,
                            const u16* __restrict__ BT, u16* __restrict__ C) {
    __shared__ u16 smem[16384];  // 32KB: At[128][64] | Bt[128][64], reused as Ct
    u16* At = smem;
    u16* Bt = smem + 8192;
    int t = threadIdx.x;
    int lane = t & 63, w = t >> 6;
    int mt = blockIdx.x >> 1, nt = blockIdx.x & 1;
    int m0 = mt * 128, n0 = nt * 128;
    int wr = (w >> 1) * 64, wc = (w & 1) * 64;
    f32x4 acc[4][4] = {};
    int q = lane >> 4, cl = lane & 15;
    int c7 = cl & 7;

    for (int ph = 0; ph < 4; ++ph) {
        int kb = ph * 64;
#pragma unroll
        for (int it = 0; it < 4; ++it) {
            int c = it * 256 + t;          // 16B chunk id 0..1023
            int row = c >> 3, c8 = c & 7;
            int sc8 = c8 ^ (row & 7);      // pre-swizzled source chunk
            gload_lds16(A + (size_t)(m0 + row) * 256 + kb + sc8 * 8, &At[c * 8]);
            gload_lds16(BT + (size_t)(n0 + row) * 256 + kb + sc8 * 8, &Bt[c * 8]);
        }
        __syncthreads();
#pragma unroll
        for (int ks = 0; ks < 2; ++ks) {
            short8 af[4], bf[4];
            int xa = ((ks * 4 + q) ^ c7) * 8;
#pragma unroll
            for (int i = 0; i < 4; ++i)
                af[i] = *(const short8*)&At[(wr + i * 16 + cl) * 64 + xa];
#pragma unroll
            for (int j = 0; j < 4; ++j)
                bf[j] = *(const short8*)&Bt[(wc + j * 16 + cl) * 64 + xa];
#pragma unroll
            for (int i = 0; i < 4; ++i)
#pragma unroll
                for (int j = 0; j < 4; ++j)
                    acc[i][j] = __builtin_amdgcn_mfma_f32_16x16x32_bf16(af[i], bf[j], acc[i][j], 0, 0, 0);
        }
        __syncthreads();
    }
    // epilogue: acc -> swizzled LDS (conflict-free) -> coalesced dwordx4 stores
    u16* Ct = smem;
    int sw_w = q << 1;
#pragma unroll
    for (int i = 0; i < 4; ++i)
#pragma unroll
        for (int j = 0; j < 4; ++j) {
            int colb = wc + j * 16 + cl;
            int chunk = (colb >> 3) ^ sw_w;
#pragma unroll
            for (int r = 0; r < 4; ++r) {
                int row = wr + i * 16 + q * 4 + r;
                Ct[row * 128 + chunk * 8 + (colb & 7)] = f2bf(acc[i][j][r]);
            }
        }
    __syncthreads();
#pragma unroll
    for (int it = 0; it < 8; ++it) {
        int c = it * 256 + t;        // 0..2047 chunks of 16 B
        int row = c >> 4, k16 = c & 15;
        int mrow = m0 + row;
        if (mrow < NN) {
            int phys = k16 ^ (((row >> 2) & 3) << 1);
            float4 v = *(const float4*)&Ct[row * 128 + phys * 8];
            *(float4*)&C[(size_t)mrow * 256 + n0 + k16 * 8] = v;
        }
    }
}

// ---- layer-1 aggregation: inline weights (bf16 el1b probe + exp) + gather +
// bf16 residual + fused eler2 (el2 packed bf16) ----
__global__ void k_agg1(const int* __restrict__ rowptr, const int* __restrict__ csrc,
                       const u16* __restrict__ el1b, const float* __restrict__ er1,
                       const u16* __restrict__ fs, u16* __restrict__ hb,
                       const float* __restrict__ wl2, const float* __restrict__ wr2,
                       u16* __restrict__ el2b, float* __restrict__ er2) {
    int wave = threadIdx.x >> 6, lane = threadIdx.x & 63;
    int node = blockIdx.x * 4 + wave;
    int beg = rowptr[node], end = rowptr[node + 1];
    int head = lane >> 4;
    float erh = er1[node * 4 + head];
    const u16* elh = el1b + head;
    float a0 = 0.f, a1 = 0.f, a2 = 0.f, a3 = 0.f, ll = 0.f;
#pragma unroll 8
    for (int p = beg; p < end; ++p) {
        int s = csrc[p];
        float x = bf2f(elh[(size_t)s * 4]) + erh;
        x = x > 0.f ? x : 0.2f * x;
        x = fminf(fmaxf(x, -60.f), 60.f);
        float pw = __expf(x);
        ushort4 fv = *(const ushort4*)(fs + (size_t)s * 256 + lane * 4);
        ll += pw;
        a0 += pw * bf2f(fv.x);
        a1 += pw * bf2f(fv.y);
        a2 += pw * bf2f(fv.z);
        a3 += pw * bf2f(fv.w);
    }
    float rinv = 1.f / ll;
    ushort4 rv = ((const ushort4*)hb)[(size_t)node * 64 + lane];
    float v0 = a0 * rinv + bf2f(rv.x), v1 = a1 * rinv + bf2f(rv.y);
    float v2 = a2 * rinv + bf2f(rv.z), v3 = a3 * rinv + bf2f(rv.w);
    v0 = v0 > 0.f ? v0 : __expf(v0) - 1.f;
    v1 = v1 > 0.f ? v1 : __expf(v1) - 1.f;
    v2 = v2 > 0.f ? v2 : __expf(v2) - 1.f;
    v3 = v3 > 0.f ? v3 : __expf(v3) - 1.f;
    ushort4 o = {f2bf(v0), f2bf(v1), f2bf(v2), f2bf(v3)};
    ((ushort4*)hb)[(size_t)node * 64 + lane] = o;
    // fused eler2: lane owns h1 cols lane*4..+3
    float4 w0 = ((const float4*)wl2)[lane * 4 + 0];
    float4 w1 = ((const float4*)wl2)[lane * 4 + 1];
    float4 w2 = ((const float4*)wl2)[lane * 4 + 2];
    float4 w3 = ((const float4*)wl2)[lane * 4 + 3];
    float4 r0 = ((const float4*)wr2)[lane * 4 + 0];
    float4 r1 = ((const float4*)wr2)[lane * 4 + 1];
    float4 r2 = ((const float4*)wr2)[lane * 4 + 2];
    float4 r3 = ((const float4*)wr2)[lane * 4 + 3];
    float acl[4], acr[4];
    acl[0] = v0 * w0.x + v1 * w1.x + v2 * w2.x + v3 * w3.x;
    acl[1] = v0 * w0.y + v1 * w1.y + v2 * w2.y + v3 * w3.y;
    acl[2] = v0 * w0.z + v1 * w1.z + v2 * w2.z + v3 * w3.z;
    acl[3] = v0 * w0.w + v1 * w1.w + v2 * w2.w + v3 * w3.w;
    acr[0] = v0 * r0.x + v1 * r1.x + v2 * r2.x + v3 * r3.x;
    acr[1] = v0 * r0.y + v1 * r1.y + v2 * r2.y + v3 * r3.y;
    acr[2] = v0 * r0.z + v1 * r1.z + v2 * r2.z + v3 * r3.z;
    acr[3] = v0 * r0.w + v1 * r1.w + v2 * r2.w + v3 * r3.w;
#pragma unroll
    for (int off = 32; off > 0; off >>= 1) {
#pragma unroll
        for (int t = 0; t < 4; ++t) {
            acl[t] += __shfl_down(acl[t], off, 64);
            acr[t] += __shfl_down(acr[t], off, 64);
        }
    }
    if (lane == 0) {
        ushort4 eb = {f2bf(acl[0]), f2bf(acl[1]), f2bf(acl[2]), f2bf(acl[3])};
        ((ushort4*)el2b)[node] = eb;
        float4 vr = {acr[0], acr[1], acr[2], acr[3]};
        ((float4*)er2)[node] = vr;
    }
}

// ---- layer-2 aggregation: inline weights (bf16 el2b probe) + residual + head-mean ----
__global__ void k_agg2(const int* __restrict__ rowptr, const int* __restrict__ csrc,
                       const u16* __restrict__ el2b, const float* __restrict__ er2,
                       const u16* __restrict__ c2,
                       void* __restrict__ out, const int* __restrict__ mode) {
    bool f32m = (*mode) != 0;
    int wave = threadIdx.x >> 6, lane = threadIdx.x & 63;
    int node = blockIdx.x * 4 + wave;
    int beg = rowptr[node], end = rowptr[node + 1];
    int head = lane >> 4;
    float erh = er2[node * 4 + head];
    const u16* elh = el2b + head;
    float a0 = 0.f, a1 = 0.f, ll = 0.f;
#pragma unroll 8
    for (int p = beg; p < end; ++p) {
        int s = csrc[p];
        float x = bf2f(elh[(size_t)s * 4]) + erh;
        x = x > 0.f ? x : 0.2f * x;
        x = fminf(fmaxf(x, -60.f), 60.f);
        float pw = __expf(x);
        ushort2 fv = *(const ushort2*)(c2 + (size_t)s * 256 + lane * 2);
        ll += pw;
        a0 += pw * bf2f(fv.x);
        a1 += pw * bf2f(fv.y);
    }
    float rinv = 1.f / ll;
    ushort2 rv = *(const ushort2*)(c2 + (size_t)node * 256 + 128 + lane * 2);
    float o0 = a0 * rinv + bf2f(rv.x);
    float o1 = a1 * rinv + bf2f(rv.y);
    o0 += __shfl_xor(o0, 16, 64); o0 += __shfl_xor(o0, 32, 64);
    o1 += __shfl_xor(o1, 16, 64); o1 += __shfl_xor(o1, 32, 64);
    if (lane < 16) {
        float v0 = 0.25f * o0, v1 = 0.25f * o1;
        size_t oi = (size_t)node * 32 + lane * 2;
        if (f32m) {
            ((float*)out)[oi] = v0;
            ((float*)out)[oi + 1] = v1;
        } else {
            ushort2 ov = {f2bf(v0), f2bf(v1)};
            *(ushort2*)((u16*)out + oi) = ov;
        }
    }
}

extern "C" void kernel_launch(void* const* d_in, const int* in_sizes, int n_in,
                              void* d_out, int out_size, void* d_ws, size_t ws_size,
                              hipStream_t stream) {
    int ih = 0, isrc = 1, idst = 2, iW1s = 3, iW1d = 4, ial1 = 5, iar1 = 6,
        iW2s = 7, iW2d = 8, ial2 = 9, iar2 = 10, iWres = 11;
    if (n_in >= 12 && in_sizes[0] != 12800000) {
        iW1d = 0; iW1s = 1; iW2d = 2; iW2s = 3; iWres = 4; ial1 = 5; ial2 = 6;
        iar1 = 7; iar2 = 8; idst = 9; ih = 10; isrc = 11;
    }
    const void* h     = d_in[ih];
    const int* src    = (const int*)d_in[isrc];
    const int* dst    = (const int*)d_in[idst];
    const void* W1s   = d_in[iW1s];
    const void* W1d   = d_in[iW1d];
    const void* al1   = d_in[ial1];
    const void* ar1   = d_in[iar1];
    const void* W2s   = d_in[iW2s];
    const void* W2d   = d_in[iW2d];
    const void* al2   = d_in[ial2];
    const void* ar2   = d_in[iar2];
    const void* Wres2 = d_in[iWres];

    char* w = (char*)d_ws;
    size_t off = 0;
    auto alloc = [&](size_t bytes) -> void* {
        void* p = w + off;
        off += (bytes + 255) & ~(size_t)255;
        return p;
    };
    int* mode   = (int*)alloc(256);
    float* wl1 = (float*)alloc(256 * 4 * 4);
    float* wr1 = (float*)alloc(256 * 4 * 4);
    float* wl2 = (float*)alloc(256 * 4 * 4);
    float* wr2 = (float*)alloc(256 * 4 * 4);
    int* deg    = (int*)alloc(NN * 4);
    int* rowptr = (int*)alloc((NN + 1) * 4);
    int* bsum   = (int*)alloc(NBLK_SCAN * 4);
    int* eorder = (int*)alloc((size_t)EE * 4);
    int* csrc   = (int*)alloc((size_t)EE * 4);         // 3.4 MB CSR src index
    u16* el1b   = (u16*)alloc((size_t)NN * 4 * 2);     // 400 KB bf16 attn-l table
    float* er1  = (float*)alloc((size_t)NN * 4 * 4);
    u16* el2b   = (u16*)alloc((size_t)NN * 4 * 2);
    float* er2  = (float*)alloc((size_t)NN * 4 * 4);
    u16* BT1    = (u16*)alloc(256 * 256 * 2);
    u16* BT2    = (u16*)alloc(256 * 256 * 2);
    u16* fs1    = (u16*)alloc((size_t)NN * 256 * 2);          // 25.6 MB
    u16* hb     = (u16*)alloc((size_t)(NN + 64) * 256 * 2);   // +64 rows slack (GEMM OOB tile reads)
    u16* c2     = fs1;   // fs1 dead after k_agg1; c2 = [fs2 | res2]

    // 1: detect + zero deg
    k_detect<<<197, 256, 0, stream>>>((const u16*)h, mode, deg);
    // 2: tiled B-transpose + attn vecs + deg count + edge ranks
    k_prep<<<48 + (EE + 255) / 256, 256, 0, stream>>>(
        W1s, al1, W1d, ar1, W2s, al2, W2d, ar2, Wres2, dst,
        BT1, BT2, wl1, wr1, wl2, wr2, deg, eorder, mode);
    // 3: scan stage 1
    k_scan1<<<NBLK_SCAN, 512, 0, stream>>>(deg, rowptr, bsum);
    // 4: scan finalize + eler1 (el1 packed bf16) + h->bf16 (hb)
    k_scan3_eler1<<<196 + NN / 4, 256, 0, stream>>>(rowptr, bsum,
                                                    h, hb, wl1, wr1, el1b, er1, mode);
    // 5: pure CSR scatter (weights computed inline in agg kernels)
    k_scat<<<(EE + 255) / 256, 256, 0, stream>>>(src, dst, eorder, rowptr, csrc);
    // 6: layer-1 GEMM (A = hb bf16, global_load_lds staging)
    k_gemm_mfma<<<782, 256, 0, stream>>>(hb, BT1, fs1);
    // 7: layer-1 aggregation, inline weights + fused eler2 (el2 packed bf16)
    k_agg1<<<NN / 4, 256, 0, stream>>>(rowptr, csrc, el1b, er1, fs1, hb,
                                       wl2, wr2, el2b, er2);
    // 8: layer-2 fused GEMM [W2s | Wres2] (A = h1 in hb)
    k_gemm_mfma<<<782, 256, 0, stream>>>(hb, BT2, c2);
    // 9: layer-2 aggregation, inline weights
    k_agg2<<<NN / 4, 256, 0, stream>>>(rowptr, csrc, el2b, er2, c2, d_out, mode);
}